// Round 7
// baseline (682.004 us; speedup 1.0000x reference)
//
#include <hip/hip_runtime.h>
#include <math.h>

typedef unsigned int u32;
typedef __attribute__((ext_vector_type(2))) _Float16 h2;

#define kT 32
#define OUT_STATES 1048576   // T*B*D
#define OUT_M      1179648   // + 4*B*D

union H2U { u32 u; h2 h; };

__device__ __forceinline__ float dot2u(u32 w, u32 x, float acc){
  H2U a; a.u = w; H2U b; b.u = x;
#if __has_builtin(__builtin_amdgcn_fdot2)
  return __builtin_amdgcn_fdot2(a.h, b.h, acc, false);
#else
  acc += (float)a.h.x * (float)b.h.x;
  acc += (float)a.h.y * (float)b.h.y;
  return acc;
#endif
}

__device__ __forceinline__ u32 packf16(float x, float y){
  H2U v; v.h.x = (_Float16)x; v.h.y = (_Float16)y; return v.u;
}

__device__ __forceinline__ u32 alu(const u32* p){
  return __hip_atomic_load((u32*)p, __ATOMIC_RELAXED, __HIP_MEMORY_SCOPE_AGENT);
}
__device__ __forceinline__ float alf(const float* p){
  return __hip_atomic_load((float*)p, __ATOMIC_RELAXED, __HIP_MEMORY_SCOPE_AGENT);
}
__device__ __forceinline__ void asu(u32* p, u32 v){
  __hip_atomic_store(p, v, __ATOMIC_RELAXED, __HIP_MEMORY_SCOPE_AGENT);
}
__device__ __forceinline__ void asf(float* p, float v){
  __hip_atomic_store(p, v, __ATOMIC_RELAXED, __HIP_MEMORY_SCOPE_AGENT);
}

// wave 0 polls n flags (n<=64), then block barrier
__device__ __forceinline__ void pollk(const u32* f, int n, u32 tgt, int tid){
  if (tid < 64){
    const u32* p = f + ((tid < n) ? tid : 0);
    for (;;){
      if (__all((int)(alu(p) >= tgt))) break;
      __builtin_amdgcn_s_sleep(2);
    }
  }
  __syncthreads();
}

// ---- prep: weights -> packed f16 [k/2][col] layout (coalesced source reads),
//      biases summed, wcs, mask, flags zeroed.
__global__ __launch_bounds__(1024) void k_prep(
        const float* __restrict__ Wih_r, const float* __restrict__ Whh_r,
        const float* __restrict__ bih_r, const float* __restrict__ bhh_r,
        const float* __restrict__ Wc,    const float* __restrict__ bc,
        const float* __restrict__ Wih_w, const float* __restrict__ Whh_w,
        const float* __restrict__ bih_w, const float* __restrict__ bhh_w,
        const unsigned char* __restrict__ maskraw,
        u32* WAp, u32* WEp, u32* Wcp, float* bA, float* bE, float* bcf,
        float* wcs, unsigned char* mbuf, u32* flags){
  __shared__ int sb[3];
  if (threadIdx.x < 3) sb[threadIdx.x] = 0;
  __syncthreads();
  if (threadIdx.x < 512){
    unsigned char c = maskraw[threadIdx.x];
    if (c > 1u) atomicOr(&sb[0], 1);
    if ((threadIdx.x & 3) != 0 && c != 0) atomicOr(&sb[1], 1);
    if ((threadIdx.x & 3) == 1 && c == 0x3F) atomicOr(&sb[2], 1);
  }
  __syncthreads();
  int mode = (!sb[0]) ? (sb[1] ? 1 : 0) : (sb[2] ? 2 : 3);

  int idx = blockIdx.x * 1024 + threadIdx.x;
  if (idx < 262144){
    int col = idx >> 8, kp = idx & 255;      // consecutive threads -> consec k
    int k0 = 2 * kp;
    float v0 = (k0 < 256) ? Wih_r[col * 256 + k0] : Whh_r[col * 256 + k0 - 256];
    float v1 = (k0 < 256) ? Wih_r[col * 256 + k0 + 1]
                          : Whh_r[col * 256 + k0 + 1 - 256];
    WAp[kp * 1024 + col] = packf16(v0, v1);
  } else if (idx < 524288){
    int i = idx - 262144;
    int col = i >> 8, kp = i & 255;
    int k0 = 2 * kp;
    float v0 = (k0 < 256) ? Wih_w[col * 256 + k0] : Whh_w[col * 256 + k0 - 256];
    float v1 = (k0 < 256) ? Wih_w[col * 256 + k0 + 1]
                          : Whh_w[col * 256 + k0 + 1 - 256];
    WEp[kp * 1024 + col] = packf16(v0, v1);
  } else if (idx < 589824){
    int i = idx - 524288;
    int col = i >> 8, kp = i & 255;
    Wcp[kp * 256 + col] = packf16(Wc[col * 512 + 2 * kp], Wc[col * 512 + 2 * kp + 1]);
  } else if (idx < 590848){
    int i = idx - 589824;
    bA[i] = bih_r[i] + bhh_r[i];
  } else if (idx < 591872){
    int i = idx - 590848;
    bE[i] = bih_w[i] + bhh_w[i];
  } else if (idx < 592128){
    int i = idx - 591872;
    bcf[i] = bc[i];
  } else if (idx < 592384){
    int c = idx - 592128;
    float s = 0.f;
    for (int k = 0; k < 256; k++) s += Wc[c * 512 + 256 + k];
    wcs[c] = s;
  } else if (idx < 723456){
    int l = idx - 592384;
    unsigned char mv;
    if      (mode == 0) mv = (((const int*)maskraw)[l] != 0);
    else if (mode == 1) mv = (maskraw[l] != 0);
    else if (mode == 2) mv = ((maskraw[2*l] | maskraw[2*l+1]) != 0);
    else                mv = (((const unsigned int*)maskraw)[l] != 0);
    mbuf[l] = mv;
  } else if (idx < 724224){
    flags[idx - 723456] = 0;   // fR 128 | (unused 64) | fG 64 | fW 64 | fT0 256
  }
}

// ---- k_pre: gxp[t][b][cp] = packed f16 pairs of (emb[t,b,:] @ Wih_r^T) ------
__global__ __launch_bounds__(1024) void k_pre(
        const float* __restrict__ emb, const u32* __restrict__ WAp,
        u32* __restrict__ gxp){
  __shared__ u32 wt[16384];          // [kp 128][c 128]
  __shared__ u32 xt[128 * 129];      // [b][kp] padded
  int t = blockIdx.x, c0 = blockIdx.y * 128, tid = threadIdx.x;
  for (int i = 0; i < 16; i++){
    int idx = i * 1024 + tid;
    wt[idx] = WAp[(size_t)(idx >> 7) * 1024 + c0 + (idx & 127)];
    int b = idx >> 7, kp = idx & 127;
    float2 e2 = *(const float2*)(emb + (size_t)t * 32768 + b * 256 + 2 * kp);
    xt[b * 129 + kp] = packf16(e2.x, e2.y);
  }
  __syncthreads();
  int b = tid & 127, cg = tid >> 7;
  float acc[16];
  #pragma unroll
  for (int j = 0; j < 16; j++) acc[j] = 0.f;
  const u32* xrow = xt + b * 129;
  for (int kp = 0; kp < 128; kp++){
    u32 xv = xrow[kp];
    const uint4* wr = (const uint4*)(wt + kp * 128 + cg * 16);
    #pragma unroll
    for (int j4 = 0; j4 < 4; j4++){
      uint4 wv = wr[j4];
      acc[4*j4+0] = dot2u(wv.x, xv, acc[4*j4+0]);
      acc[4*j4+1] = dot2u(wv.y, xv, acc[4*j4+1]);
      acc[4*j4+2] = dot2u(wv.z, xv, acc[4*j4+2]);
      acc[4*j4+3] = dot2u(wv.w, xv, acc[4*j4+3]);
    }
  }
  u32* gp = gxp + ((size_t)t * 128 + b) * 512 + (c0 >> 1) + cg * 8;
  #pragma unroll
  for (int i = 0; i < 8; i++) gp[i] = packf16(acc[2*i], acc[2*i+1]);
}

// gemv: 1024 cols, K=256 (128 half2 rows). thread = (cg: 4 cols, ks: 4 slices)
__device__ __forceinline__ void gemv256(const u32* __restrict__ W,
        const u32* xh, float* psum, int tid){
  int cg = tid & 255, ks = tid >> 8;
  const uint4* wp = (const uint4*)W + (size_t)ks * 32 * 256 + cg;
  const u32* xk = xh + ks * 32;
  float a0 = 0.f, a1 = 0.f, a2 = 0.f, a3 = 0.f;
  #pragma unroll 8
  for (int i = 0; i < 32; i++){
    uint4 wv = wp[(size_t)i * 256];
    u32 xp = xk[i];
    a0 = dot2u(wv.x, xp, a0);  a1 = dot2u(wv.y, xp, a1);
    a2 = dot2u(wv.z, xp, a2);  a3 = dot2u(wv.w, xp, a3);
  }
  float4 r; r.x = a0; r.y = a1; r.z = a2; r.w = a3;
  *(float4*)&psum[ks * 1024 + cg * 4] = r;
}

// gemv: 256 cols, K=128 half2 rows. thread = (c: 1 col, ks: 4 slices of 32)
__device__ __forceinline__ void gemv128x256(const u32* __restrict__ W,
        const u32* xh, float* psum, int tid){
  int c = tid & 255, ks = tid >> 8;
  const u32* wp = W + (size_t)(ks * 32) * 256 + c;
  const u32* xk = xh + ks * 32;
  float a = 0.f;
  #pragma unroll 8
  for (int i = 0; i < 32; i++) a = dot2u(wp[(size_t)i * 256], xk[i], a);
  psum[ks * 256 + c] = a;
}

// ---- distributed t=0 flash scan: block k scans row k>>1, half k&1 (512 l) ---
__device__ void scan_half(int k, const float* __restrict__ M0,
        const unsigned char* __restrict__ mbuf, const float* __restrict__ hrf,
        float* spbuf, float* mpbuf, float* msbuf, u32* fT0, const u32* fR,
        char* sc, int tid){
  float* ps   = (float*)(sc);            // [16][260]
  float* wred = (float*)(sc + 16640);    // [16]
  float* sred = (float*)(sc + 16704);    // [16]
  float* hr0l = (float*)(sc + 16768);    // [256]
  int row = k >> 1, half = k & 1;
  pollk(fR + row, 1, 1u, tid);
  if (tid < 256) hr0l[tid] = alf(hrf + row * 256 + tid);   // slot 0
  __syncthreads();
  int w = tid >> 6, lane = tid & 63;
  float4 hrv = *(const float4*)&hr0l[lane * 4];
  float run_max = -INFINITY, S = 0.f;
  float m0 = 0.f, m1 = 0.f, m2 = 0.f, m3 = 0.f;
  int l0 = half * 512 + w * 32;
  for (int l = l0; l < l0 + 32; ++l){
    float4 Mv = *(const float4*)(M0 + ((size_t)row * 1024 + l) * 256 + lane * 4);
    float part = Mv.x * hrv.x + Mv.y * hrv.y + Mv.z * hrv.z + Mv.w * hrv.w;
    #pragma unroll
    for (int mm = 32; mm >= 1; mm >>= 1) part += __shfl_xor(part, mm, 64);
    float s = mbuf[row * 1024 + l] ? -INFINITY : part;
    if (lane == 0) asf(spbuf + row * 1024 + l, s);
    float nm = fmaxf(run_max, s);
    if (nm > -INFINITY){
      float sc2 = expf(run_max - nm);
      float p   = expf(s - nm);
      S = S * sc2 + p;
      m0 = m0 * sc2 + p * Mv.x;  m1 = m1 * sc2 + p * Mv.y;
      m2 = m2 * sc2 + p * Mv.z;  m3 = m3 * sc2 + p * Mv.w;
      run_max = nm;
    }
  }
  if (lane == 0){ wred[w] = run_max; sred[w] = S; }
  ps[w * 260 + lane * 4 + 0] = m0;
  ps[w * 260 + lane * 4 + 1] = m1;
  ps[w * 260 + lane * 4 + 2] = m2;
  ps[w * 260 + lane * 4 + 3] = m3;
  __syncthreads();
  float gmax = -INFINITY;
  #pragma unroll
  for (int w2 = 0; w2 < 16; w2++) gmax = fmaxf(gmax, wred[w2]);
  float Sg = 0.f;
  #pragma unroll
  for (int w2 = 0; w2 < 16; w2++) Sg += sred[w2] * expf(wred[w2] - gmax);
  if (tid < 256){
    float mv = 0.f;
    #pragma unroll
    for (int w2 = 0; w2 < 16; w2++) mv += ps[w2 * 260 + tid] * expf(wred[w2] - gmax);
    asf(mpbuf + k * 256 + tid, mv);     // unnormalized, relative to gmax
  }
  if (tid == 0){ asf(msbuf + 2 * k, gmax); asf(msbuf + 2 * k + 1, Sg); }
  __syncthreads();   // drains all prior stores
  if (tid == 0) asu(fT0 + k, 1u);
}

// ---- main: 256 persistent blocks, 1 per CU GUARANTEED (LDS 84KB > 160/2).
// R [0,128):   row b: hr-chain (gxp + Whh_r) + u = Wc_hr@hr. 2-slot buffers.
// G [128,192): rows 2g,2g+1: gw = Whh_w@hw(t-1) only.
// W [192,256): rows 2g,2g+1: z-update (round-5 full reductions),
//              e = u+Ab*wcs+Cb*vc+bc with vc computed LOCALLY at prev tail,
//              round-5 softmax, Wih_w@pe, combine with gw, nonlinearity.
__global__ __launch_bounds__(1024, 4) void k_main(
        const float* __restrict__ hr0, const float* __restrict__ cr0,
        const float* __restrict__ hw0, const float* __restrict__ cw0,
        const float* __restrict__ M0,
        const u32* __restrict__ WAp, const u32* __restrict__ WEp,
        const u32* __restrict__ Wcp, const float* __restrict__ bA,
        const float* __restrict__ bE, const float* __restrict__ bcf,
        const float* __restrict__ wcs, const unsigned char* __restrict__ mbuf,
        const u32* __restrict__ gxp,
        float* __restrict__ hrf, float* __restrict__ ubuf,
        float* __restrict__ gwbuf,
        u32* __restrict__ hwp, float* __restrict__ zsbuf,
        float* __restrict__ hwfin, float* __restrict__ spbuf,
        float* __restrict__ mpbuf, float* __restrict__ msbuf,
        u32* __restrict__ flags, float* __restrict__ out){
  // 84KB static LDS: forces exactly 1 block/CU -> grid 256 == CU count,
  // all persistent blocks provably co-resident (no spin-wait deadlock).
  __shared__ __attribute__((aligned(16))) char smem[86016];
  int bid = blockIdx.x, tid = threadIdx.x;
  int w = tid >> 6, lane = tid & 63;
  u32* fR  = flags;          // 128
  u32* fG  = flags + 192;    // 64
  u32* fW  = flags + 256;    // 64
  u32* fT0 = flags + 320;    // 256

  if (bid < 128){
    // ===================== R: read-LSTM + u-gemv =====================
    int b = bid;
    float* psum = (float*)(smem);            // 16KB
    u32*  xh    = (u32*)(smem + 16384);      // 512B
    float* hr_f = (float*)(smem + 16896);    // 1KB
    const u32* WRh = WAp + 128 * 1024;       // Whh_r half
    float cst = (tid < 256) ? cr0[b * 256 + tid] : 0.f;
    if (tid < 128){
      float2 h0 = *(const float2*)(hr0 + b * 256 + 2 * tid);
      xh[tid] = packf16(h0.x, h0.y);
    }
    __syncthreads();
    for (int t = 0; t < kT; t++){
      if (t >= 2) pollk(fW + (b >> 1), 1, (u32)(t - 1), tid);  // 2-slot bp
      u32 gx0 = 0, gx1 = 0, gx2 = 0, gx3 = 0;
      if (tid < 256){
        const u32* gx = gxp + ((size_t)t * 128 + b) * 512;
        gx0 = gx[tid >> 1];          gx1 = gx[128 + (tid >> 1)];
        gx2 = gx[256 + (tid >> 1)];  gx3 = gx[384 + (tid >> 1)];
      }
      gemv256(WRh, xh, psum, tid);
      __syncthreads();
      if (tid < 256){
        H2U p0, p1, p2, p3;
        p0.u = gx0; p1.u = gx1; p2.u = gx2; p3.u = gx3;
        int hi = tid & 1;
        float gi = (hi ? (float)p0.h.y : (float)p0.h.x) + bA[tid];
        float gf = (hi ? (float)p1.h.y : (float)p1.h.x) + bA[256 + tid];
        float gg = (hi ? (float)p2.h.y : (float)p2.h.x) + bA[512 + tid];
        float go = (hi ? (float)p3.h.y : (float)p3.h.x) + bA[768 + tid];
        #pragma unroll
        for (int ks = 0; ks < 4; ks++){
          gi += psum[ks * 1024 + tid];
          gf += psum[ks * 1024 + 256 + tid];
          gg += psum[ks * 1024 + 512 + tid];
          go += psum[ks * 1024 + 768 + tid];
        }
        float i_ = 1.f / (1.f + expf(-gi));
        float f_ = 1.f / (1.f + expf(-gf));
        float g_ = tanhf(gg);
        float o_ = 1.f / (1.f + expf(-go));
        float c2 = f_ * cst + i_ * g_;
        cst = c2;
        float h = o_ * tanhf(c2);
        hr_f[tid] = h;
        asf(hrf + (t & 1) * 32768 + b * 256 + tid, h);
        if (t == kT - 1){
          out[OUT_STATES          + b * 256 + tid] = h;
          out[OUT_STATES +  32768 + b * 256 + tid] = c2;
        }
      }
      __syncthreads();
      if (tid < 128) xh[tid] = packf16(hr_f[2 * tid], hr_f[2 * tid + 1]);
      __syncthreads();
      gemv128x256(Wcp, xh, psum, tid);     // u = Wc_hr @ hr_t
      __syncthreads();
      if (tid < 256){
        float u = psum[tid] + psum[256 + tid] + psum[512 + tid] + psum[768 + tid];
        asf(ubuf + (t & 1) * 32768 + b * 256 + tid, u);
      }
      __syncthreads();   // drain before flag
      if (tid == 0) asu(fR + b, (u32)(t + 1));
      if (t == 0)
        scan_half(bid, M0, mbuf, hrf, spbuf, mpbuf, msbuf, fT0, fR,
                  smem + 49152, tid);
    }
  } else if (bid < 192){
    // ===================== G: gw gemv only (2 rows) =====================
    int g = bid - 128, r0 = 2 * g, r1 = 2 * g + 1;
    float* psum = (float*)(smem);            // 32KB
    u32*  xh    = (u32*)(smem + 32768);      // 1KB
    for (int t = 0; t < kT; t++){
      if (t == 0){
        if (tid < 128){
          float2 h0 = *(const float2*)(hw0 + r0 * 256 + 2 * tid);
          xh[tid] = packf16(h0.x, h0.y);
        } else if (tid < 256){
          int j = tid - 128;
          float2 h0 = *(const float2*)(hw0 + r1 * 256 + 2 * j);
          xh[tid] = packf16(h0.x, h0.y);
        }
      } else {
        pollk(fW + g, 1, (u32)t, tid);
        if (tid < 128)
          xh[tid] = alu(hwp + ((t - 1) & 1) * 16384 + r0 * 128 + tid);
        else if (tid < 256)
          xh[tid] = alu(hwp + ((t - 1) & 1) * 16384 + r1 * 128 + (tid - 128));
      }
      __syncthreads();
      {  // gw = Whh_w @ hw(t-1), both rows
        int cg = tid & 255, ks = tid >> 8;
        const uint4* wp = (const uint4*)(WEp + 128 * 1024)
                        + (size_t)(ks * 32) * 256 + cg;
        const u32* x0 = xh + ks * 32;
        const u32* x1 = xh + 128 + ks * 32;
        float a0=0.f,a1=0.f,a2=0.f,a3=0.f,b0=0.f,b1=0.f,b2=0.f,b3=0.f;
        #pragma unroll 4
        for (int ii = 0; ii < 32; ii++){
          uint4 wv = wp[(size_t)ii * 256];
          u32 xp0 = x0[ii], xp1 = x1[ii];
          a0 = dot2u(wv.x, xp0, a0);  a1 = dot2u(wv.y, xp0, a1);
          a2 = dot2u(wv.z, xp0, a2);  a3 = dot2u(wv.w, xp0, a3);
          b0 = dot2u(wv.x, xp1, b0);  b1 = dot2u(wv.y, xp1, b1);
          b2 = dot2u(wv.z, xp1, b2);  b3 = dot2u(wv.w, xp1, b3);
        }
        float4 ra; ra.x=a0; ra.y=a1; ra.z=a2; ra.w=a3;
        float4 rb; rb.x=b0; rb.y=b1; rb.z=b2; rb.w=b3;
        *(float4*)&psum[ks * 1024 + cg * 4] = ra;
        *(float4*)&psum[4096 + ks * 1024 + cg * 4] = rb;
      }
      __syncthreads();
      #pragma unroll
      for (int rr = 0; rr < 2; rr++){
        float v = psum[rr * 4096 + tid] + psum[rr * 4096 + 1024 + tid]
                + psum[rr * 4096 + 2048 + tid] + psum[rr * 4096 + 3072 + tid];
        asf(gwbuf + (t & 1) * 131072 + (2 * g + rr) * 1024 + tid, v);
      }
      __syncthreads();   // drain before flag
      if (tid == 0) asu(fG + g, (u32)(t + 1));
      if (t == 0)
        scan_half(bid, M0, mbuf, hrf, spbuf, mpbuf, msbuf, fT0, fR,
                  smem + 49152, tid);
    }
  } else {
    // ===================== W: z + comp + write-LSTM (2 rows) ==================
    int g = bid - 192, r0g = 2 * g;
    float* psum  = (float*)(smem);           // 32KB [2][4][1024]
    u32*  xh    = (u32*)(smem + 32768);      // 1KB
    float* comp  = (float*)(smem + 33792);   // [2][256]
    float* hw_f  = (float*)(smem + 35840);   // [2][256]
    float* m_f   = (float*)(smem + 37888);   // [2][256]
    float* wcs_l = (float*)(smem + 39936);   // [256]
    float* bc_l  = (float*)(smem + 40960);   // [256]
    float* redA  = (float*)(smem + 41984);   // [16]
    float* redB  = (float*)(smem + 42048);
    float* redC  = (float*)(smem + 42112);
    float* redD  = (float*)(smem + 42176);
    float* bE_l  = (float*)(smem + 43008);   // [1024]
    int row = tid >> 9, i = tid & 511;
    int brow = r0g + row;
    if (tid < 256){ wcs_l[tid] = wcs[tid]; bc_l[tid] = bcf[tid]; }
    bE_l[tid] = bE[tid];
    float cst = 0.f;
    if (i < 256){
      hw_f[row * 256 + i] = hw0[brow * 256 + i];
      cst = cw0[brow * 256 + i];
    }
    unsigned char mkA = mbuf[brow * 1024 + i];
    unsigned char mkB = mbuf[brow * 1024 + 512 + i];
    float zA = 0.f, zB = 0.f, vcreg = 0.f;
    __syncthreads();
    // scan duty first (publishes partials other W blocks need)
    scan_half(bid, M0, mbuf, hrf, spbuf, mpbuf, msbuf, fT0, fR,
              smem + 49152, tid);

    for (int t = 0; t < kT; t++){
      pollk(fR + r0g, 2, (u32)(t + 1), tid);
      float hrv = 0.f, ureg = 0.f;
      if (i < 256){
        hrv  = alf(hrf + (t & 1) * 32768 + brow * 256 + i);
        ureg = alf(ubuf + (t & 1) * 32768 + brow * 256 + i);
      }
      float e = -INFINITY;
      if (t == 0){
        pollk(fT0 + 4 * g, 4, 1u, tid);
        int kA2 = 2 * brow, kB2 = 2 * brow + 1;
        float maxA = alf(msbuf + 2 * kA2), SAv = alf(msbuf + 2 * kA2 + 1);
        float maxB = alf(msbuf + 2 * kB2), SBv = alf(msbuf + 2 * kB2 + 1);
        float Gm = fmaxf(maxA, maxB);
        float eAc = expf(maxA - Gm), eBc = expf(maxB - Gm);
        float Sg = SAv * eAc + SBv * eBc;
        zA = expf(alf(spbuf + brow * 1024 + i) - Gm) / Sg;
        zB = expf(alf(spbuf + brow * 1024 + 512 + i) - Gm) / Sg;
        if (i < 256){
          float mv = (alf(mpbuf + kA2 * 256 + i) * eAc
                    + alf(mpbuf + kB2 * 256 + i) * eBc) / Sg;
          m_f[row * 256 + i] = mv;
        }
        __syncthreads();
        if (i < 128)
          xh[row * 128 + i] = packf16(m_f[row * 256 + 2 * i],
                                      m_f[row * 256 + 2 * i + 1]);
        __syncthreads();
        {  // vcm = Wc_m @ m0, both rows (one-time)
          int c = tid & 255, ks = tid >> 8;
          const u32* wp = Wcp + 32768 + (size_t)(ks * 32) * 256 + c;
          const u32* x0 = xh + ks * 32;
          const u32* x1 = xh + 128 + ks * 32;
          float a0 = 0.f, a1 = 0.f;
          #pragma unroll 8
          for (int ii = 0; ii < 32; ii++){
            u32 wv = wp[(size_t)ii * 256];
            a0 = dot2u(wv, x0[ii], a0);
            a1 = dot2u(wv, x1[ii], a1);
          }
          psum[ks * 512 + c] = a0;
          psum[ks * 512 + 256 + c] = a1;
        }
        __syncthreads();
        if (i < 256){
          float vcm = psum[row * 256 + i] + psum[512 + row * 256 + i]
                    + psum[1024 + row * 256 + i] + psum[1536 + row * 256 + i];
          e = ureg + vcm + bc_l[i];
        }
      } else {
        // z-update (round-5 full reductions): M = (1-zp) + hw(t-1) (x) zp
        float v1 = (i < 256) ? hrv : 0.f;
        float v2 = (i < 256) ? hrv * hw_f[row * 256 + i] : 0.f;
        #pragma unroll
        for (int mm = 32; mm >= 1; mm >>= 1){
          v1 += __shfl_xor(v1, mm, 64);  v2 += __shfl_xor(v2, mm, 64);
        }
        if (lane == 0){ redA[w] = v1; redB[w] = v2; }
        __syncthreads();
        float S1 = 0.f, S2 = 0.f;
        #pragma unroll
        for (int k2 = 0; k2 < 8; k2++){
          S1 += redA[row * 8 + k2];  S2 += redB[row * 8 + k2];
        }
        float sA = mkA ? -INFINITY : (1.f - zA) * S1 + zA * S2;
        float sB = mkB ? -INFINITY : (1.f - zB) * S1 + zB * S2;
        float mx = fmaxf(sA, sB);
        #pragma unroll
        for (int mm = 32; mm >= 1; mm >>= 1) mx = fmaxf(mx, __shfl_xor(mx, mm, 64));
        if (lane == 0) redC[w] = mx;
        __syncthreads();
        float gm = -INFINITY;
        #pragma unroll
        for (int k2 = 0; k2 < 8; k2++) gm = fmaxf(gm, redC[row * 8 + k2]);
        float pA_ = expf(sA - gm), pB_ = expf(sB - gm);
        float ps = pA_ + pB_;
        #pragma unroll
        for (int mm = 32; mm >= 1; mm >>= 1) ps += __shfl_xor(ps, mm, 64);
        if (lane == 0) redD[w] = ps;
        __syncthreads();
        float Ss = 0.f;
        #pragma unroll
        for (int k2 = 0; k2 < 8; k2++) Ss += redD[row * 8 + k2];
        float znA = pA_ / Ss, znB = pB_ / Ss;
        float a1 = znA * (1.f - zA) + znB * (1.f - zB);
        float a2 = znA * zA + znB * zB;
        #pragma unroll
        for (int mm = 32; mm >= 1; mm >>= 1){
          a1 += __shfl_xor(a1, mm, 64);  a2 += __shfl_xor(a2, mm, 64);
        }
        if (lane == 0){ redA[w] = a1; redB[w] = a2; }
        __syncthreads();
        float Ab = 0.f, Cb = 0.f;
        #pragma unroll
        for (int k2 = 0; k2 < 8; k2++){
          Ab += redA[row * 8 + k2];  Cb += redB[row * 8 + k2];
        }
        zA = znA;  zB = znB;
        if (i < 256)
          e = ureg + Ab * wcs_l[i] + Cb * vcreg + bc_l[i];   // vc local (tail)
      }
      // softmax over 256 per row (round-5: true max; pe unnormalized)
      float ev = (i < 256) ? e : -INFINITY;
      float mx2 = ev;
      #pragma unroll
      for (int mm = 32; mm >= 1; mm >>= 1) mx2 = fmaxf(mx2, __shfl_xor(mx2, mm, 64));
      if (lane == 0) redC[w] = mx2;
      __syncthreads();
      float emax = -INFINITY;
      #pragma unroll
      for (int k2 = 0; k2 < 8; k2++) emax = fmaxf(emax, redC[row * 8 + k2]);
      float pe = (i < 256) ? expf(ev - emax) : 0.f;
      float ps2 = pe;
      #pragma unroll
      for (int mm = 32; mm >= 1; mm >>= 1) ps2 += __shfl_xor(ps2, mm, 64);
      if (lane == 0) redD[w] = ps2;
      if (i < 256) comp[row * 256 + i] = pe;
      __syncthreads();
      float esum = 0.f;
      #pragma unroll
      for (int k2 = 0; k2 < 8; k2++) esum += redD[row * 8 + k2];
      if (i < 128)
        xh[row * 128 + i] = packf16(comp[row * 256 + 2 * i],
                                    comp[row * 256 + 2 * i + 1]);
      __syncthreads();
      {  // Wih_w @ pe, both rows
        int cg = tid & 255, ks = tid >> 8;
        const uint4* wp = (const uint4*)WEp + (size_t)(ks * 32) * 256 + cg;
        const u32* x0 = xh + ks * 32;
        const u32* x1 = xh + 128 + ks * 32;
        float a0=0.f,a1=0.f,a2=0.f,a3=0.f,b0=0.f,b1=0.f,b2=0.f,b3=0.f;
        #pragma unroll 4
        for (int ii = 0; ii < 32; ii++){
          uint4 wv = wp[(size_t)ii * 256];
          u32 xp0 = x0[ii], xp1 = x1[ii];
          a0 = dot2u(wv.x, xp0, a0);  a1 = dot2u(wv.y, xp0, a1);
          a2 = dot2u(wv.z, xp0, a2);  a3 = dot2u(wv.w, xp0, a3);
          b0 = dot2u(wv.x, xp1, b0);  b1 = dot2u(wv.y, xp1, b1);
          b2 = dot2u(wv.z, xp1, b2);  b3 = dot2u(wv.w, xp1, b3);
        }
        float4 ra; ra.x=a0; ra.y=a1; ra.z=a2; ra.w=a3;
        float4 rb; rb.x=b0; rb.y=b1; rb.z=b2; rb.w=b3;
        *(float4*)&psum[ks * 1024 + cg * 4] = ra;
        *(float4*)&psum[4096 + ks * 1024 + cg * 4] = rb;
      }
      __syncthreads();
      pollk(fG + g, 1, (u32)(t + 1), tid);
      if (i < 256){
        float rinv = 1.f / esum;
        const float* gwp = gwbuf + (t & 1) * 131072 + brow * 1024;
        float si = psum[row*4096 + i]        + psum[row*4096 + 1024 + i]
                 + psum[row*4096 + 2048 + i] + psum[row*4096 + 3072 + i];
        float sf = psum[row*4096 + 256 + i]  + psum[row*4096 + 1280 + i]
                 + psum[row*4096 + 2304 + i] + psum[row*4096 + 3328 + i];
        float sg2= psum[row*4096 + 512 + i]  + psum[row*4096 + 1536 + i]
                 + psum[row*4096 + 2560 + i] + psum[row*4096 + 3584 + i];
        float so = psum[row*4096 + 768 + i]  + psum[row*4096 + 1792 + i]
                 + psum[row*4096 + 2816 + i] + psum[row*4096 + 3840 + i];
        float gi = bE_l[i]       + alf(gwp + i)       + si  * rinv;
        float gf = bE_l[256 + i] + alf(gwp + 256 + i) + sf  * rinv;
        float gg = bE_l[512 + i] + alf(gwp + 512 + i) + sg2 * rinv;
        float go = bE_l[768 + i] + alf(gwp + 768 + i) + so  * rinv;
        float i_ = 1.f / (1.f + expf(-gi));
        float f_ = 1.f / (1.f + expf(-gf));
        float g_ = tanhf(gg);
        float o_ = 1.f / (1.f + expf(-go));
        float c2 = f_ * cst + i_ * g_;
        cst = c2;
        float h = o_ * tanhf(c2);
        hw_f[row * 256 + i] = h;
        out[(size_t)t * 32768 + brow * 256 + i] = h;
        if (t == kT - 1){
          out[OUT_STATES + 65536 + brow * 256 + i] = h;
          out[OUT_STATES + 98304 + brow * 256 + i] = c2;
        }
      }
      __syncthreads();
      if (i < 128)
        asu(hwp + (t & 1) * 16384 + brow * 128 + i,
            packf16(hw_f[row * 256 + 2 * i], hw_f[row * 256 + 2 * i + 1]));
      __syncthreads();   // drain before flag
      if (tid == 0) asu(fW + g, (u32)(t + 1));
      if (t < kT - 1){
        // NEW tail: local vc = Wc_m @ hw(t) for next step's e
        if (i < 128)
          xh[row * 128 + i] = packf16(hw_f[row * 256 + 2 * i],
                                      hw_f[row * 256 + 2 * i + 1]);
        __syncthreads();
        {
          int c = tid & 255, ks = tid >> 8;
          const u32* wp = Wcp + 32768 + (size_t)(ks * 32) * 256 + c;
          const u32* x0 = xh + ks * 32;
          const u32* x1 = xh + 128 + ks * 32;
          float a0 = 0.f, a1 = 0.f;
          #pragma unroll 8
          for (int ii = 0; ii < 32; ii++){
            u32 wv = wp[(size_t)ii * 256];
            a0 = dot2u(wv, x0[ii], a0);
            a1 = dot2u(wv, x1[ii], a1);
          }
          psum[ks * 512 + c] = a0;
          psum[ks * 512 + 256 + c] = a1;
        }
        __syncthreads();
        if (i < 256)
          vcreg = psum[row * 256 + i] + psum[512 + row * 256 + i]
                + psum[1024 + row * 256 + i] + psum[1536 + row * 256 + i];
        __syncthreads();
      }
    }
    // publish final z & hw for the M epilogue
    if (i < 256) asf(hwfin + brow * 256 + i, hw_f[row * 256 + i]);
    asf(zsbuf + brow * 1024 + i, zA);
    asf(zsbuf + brow * 1024 + 512 + i, zB);
    __syncthreads();   // drain before flag
    if (tid == 0) asu(fW + g, (u32)(kT + 1));
  }

  // ========== epilogue: every block writes half a row of M ==========
  {
    int mrow = bid >> 1, half = bid & 1;
    pollk(fW + (mrow >> 1), 1, (u32)(kT + 1), tid);
    float* zl  = (float*)(smem + 49152);   // [512]
    float* hwl = (float*)(smem + 51200);   // [256]
    if (tid < 512) zl[tid] = alf(zsbuf + mrow * 1024 + half * 512 + tid);
    else if (tid < 768) hwl[tid - 512] = alf(hwfin + mrow * 256 + (tid - 512));
    __syncthreads();
    float* Mout = out + OUT_M + (size_t)mrow * 262144 + (size_t)half * 131072;
    for (int it = 0; it < 32; it++){
      int idx = it * 1024 + tid;
      int l = idx >> 6, d4 = (idx & 63) << 2;
      float z = zl[l], omz = 1.f - z;
      float4 h4 = *(const float4*)&hwl[d4];
      float4 v;
      v.x = omz + h4.x * z;  v.y = omz + h4.y * z;
      v.z = omz + h4.z * z;  v.w = omz + h4.w * z;
      *(float4*)(Mout + (size_t)l * 256 + d4) = v;
    }
  }
}

extern "C" void kernel_launch(void* const* d_in, const int* in_sizes, int n_in,
                              void* d_out, int out_size, void* d_ws, size_t ws_size,
                              hipStream_t stream){
  const float* emb   = (const float*)d_in[0];
  const float* hr0   = (const float*)d_in[1];
  const float* cr0   = (const float*)d_in[2];
  const float* hw0   = (const float*)d_in[3];
  const float* cw0   = (const float*)d_in[4];
  const float* M0    = (const float*)d_in[5];
  const unsigned char* maskraw = (const unsigned char*)d_in[6];
  const float* Wih_r = (const float*)d_in[7];
  const float* Whh_r = (const float*)d_in[8];
  const float* bih_r = (const float*)d_in[9];
  const float* bhh_r = (const float*)d_in[10];
  const float* Wc    = (const float*)d_in[11];
  const float* bc    = (const float*)d_in[12];
  const float* Wih_w = (const float*)d_in[13];
  const float* Whh_w = (const float*)d_in[14];
  const float* bih_w = (const float*)d_in[15];
  const float* bhh_w = (const float*)d_in[16];
  float* out = (float*)d_out;

  char* ws = (char*)d_ws;
  u32*  WAp   = (u32*)(ws);                       // 1 MB
  u32*  WEp   = (u32*)(ws + 1048576);             // 1 MB
  u32*  Wcp   = (u32*)(ws + 2097152);             // 256 KB
  float* bA   = (float*)(ws + 2359296);           // 4 KB
  float* bE   = (float*)(ws + 2363392);           // 4 KB
  float* bcf  = (float*)(ws + 2367488);           // 1 KB
  float* wcs  = (float*)(ws + 2368512);           // 1 KB
  unsigned char* mbuf = (unsigned char*)(ws + 2369536);  // 128 KB
  u32*  flags = (u32*)(ws + 2500608);             // 4 KB (768 zeroed)
  float* hrf  = (float*)(ws + 2504704);           // 256 KB (2 slots)
  float* ubuf = (float*)(ws + 2766848);           // 256 KB
  float* gwbuf= (float*)(ws + 3291136);           // 1 MB (2 slots)
  u32*  hwp   = (u32*)(ws + 4339712);             // 128 KB
  float* zsbuf= (float*)(ws + 4470784);           // 512 KB
  float* hwfin= (float*)(ws + 4995072);           // 128 KB
  float* spbuf= (float*)(ws + 5126144);           // 512 KB (raw t0 scores)
  float* mpbuf= (float*)(ws + 5650432);           // 256 KB (t0 partial m)
  float* msbuf= (float*)(ws + 5912576);           // 2 KB   (t0 {max,S})
  u32*  gxp   = (u32*)(ws + 5914624);             // 8 MB

  k_prep<<<dim3(708), dim3(1024), 0, stream>>>(
      Wih_r, Whh_r, bih_r, bhh_r, Wc, bc, Wih_w, Whh_w, bih_w, bhh_w,
      maskraw, WAp, WEp, Wcp, bA, bE, bcf, wcs, mbuf, flags);
  k_pre<<<dim3(32, 8), dim3(1024), 0, stream>>>(emb, WAp, gxp);
  k_main<<<dim3(256), dim3(1024), 0, stream>>>(
      hr0, cr0, hw0, cw0, M0, WAp, WEp, Wcp, bA, bE, bcf, wcs, mbuf, gxp,
      hrf, ubuf, gwbuf, hwp, zsbuf, hwfin, spbuf, mpbuf, msbuf,
      flags, out);
}

// Round 8
// 654.699 us; speedup vs baseline: 1.0417x; 1.0417x over previous
//
#include <hip/hip_runtime.h>
#include <math.h>

typedef unsigned int u32;
typedef __attribute__((ext_vector_type(2))) _Float16 h2;

#define kT 32
#define OUT_STATES 1048576   // T*B*D
#define OUT_M      1179648   // + 4*B*D

union H2U { u32 u; h2 h; };

__device__ __forceinline__ float dot2u(u32 w, u32 x, float acc){
  H2U a; a.u = w; H2U b; b.u = x;
#if __has_builtin(__builtin_amdgcn_fdot2)
  return __builtin_amdgcn_fdot2(a.h, b.h, acc, false);
#else
  acc += (float)a.h.x * (float)b.h.x;
  acc += (float)a.h.y * (float)b.h.y;
  return acc;
#endif
}

__device__ __forceinline__ u32 packf16(float x, float y){
  H2U v; v.h.x = (_Float16)x; v.h.y = (_Float16)y; return v.u;
}

__device__ __forceinline__ u32 alu(const u32* p){
  return __hip_atomic_load((u32*)p, __ATOMIC_RELAXED, __HIP_MEMORY_SCOPE_AGENT);
}
__device__ __forceinline__ float alf(const float* p){
  return __hip_atomic_load((float*)p, __ATOMIC_RELAXED, __HIP_MEMORY_SCOPE_AGENT);
}
__device__ __forceinline__ void asu(u32* p, u32 v){
  __hip_atomic_store(p, v, __ATOMIC_RELAXED, __HIP_MEMORY_SCOPE_AGENT);
}
__device__ __forceinline__ void asf(float* p, float v){
  __hip_atomic_store(p, v, __ATOMIC_RELAXED, __HIP_MEMORY_SCOPE_AGENT);
}

// wave 0 polls n flags (n<=64), then block barrier
__device__ __forceinline__ void pollk(const u32* f, int n, u32 tgt, int tid){
  if (tid < 64){
    const u32* p = f + ((tid < n) ? tid : 0);
    for (;;){
      if (__all((int)(alu(p) >= tgt))) break;
      __builtin_amdgcn_s_sleep(2);
    }
  }
  __syncthreads();
}

// ---- prep: weights -> packed f16 [k/2][col] layout (coalesced source reads),
//      biases summed, wcs, mask, flags zeroed.
__global__ __launch_bounds__(1024) void k_prep(
        const float* __restrict__ Wih_r, const float* __restrict__ Whh_r,
        const float* __restrict__ bih_r, const float* __restrict__ bhh_r,
        const float* __restrict__ Wc,    const float* __restrict__ bc,
        const float* __restrict__ Wih_w, const float* __restrict__ Whh_w,
        const float* __restrict__ bih_w, const float* __restrict__ bhh_w,
        const unsigned char* __restrict__ maskraw,
        u32* WAp, u32* WEp, u32* Wcp, float* bA, float* bE, float* bcf,
        float* wcs, unsigned char* mbuf, u32* flags){
  __shared__ int sb[3];
  if (threadIdx.x < 3) sb[threadIdx.x] = 0;
  __syncthreads();
  if (threadIdx.x < 512){
    unsigned char c = maskraw[threadIdx.x];
    if (c > 1u) atomicOr(&sb[0], 1);
    if ((threadIdx.x & 3) != 0 && c != 0) atomicOr(&sb[1], 1);
    if ((threadIdx.x & 3) == 1 && c == 0x3F) atomicOr(&sb[2], 1);
  }
  __syncthreads();
  int mode = (!sb[0]) ? (sb[1] ? 1 : 0) : (sb[2] ? 2 : 3);

  int idx = blockIdx.x * 1024 + threadIdx.x;
  if (idx < 262144){
    int col = idx >> 8, kp = idx & 255;      // consecutive threads -> consec k
    int k0 = 2 * kp;
    float v0 = (k0 < 256) ? Wih_r[col * 256 + k0] : Whh_r[col * 256 + k0 - 256];
    float v1 = (k0 < 256) ? Wih_r[col * 256 + k0 + 1]
                          : Whh_r[col * 256 + k0 + 1 - 256];
    WAp[kp * 1024 + col] = packf16(v0, v1);
  } else if (idx < 524288){
    int i = idx - 262144;
    int col = i >> 8, kp = i & 255;
    int k0 = 2 * kp;
    float v0 = (k0 < 256) ? Wih_w[col * 256 + k0] : Whh_w[col * 256 + k0 - 256];
    float v1 = (k0 < 256) ? Wih_w[col * 256 + k0 + 1]
                          : Whh_w[col * 256 + k0 + 1 - 256];
    WEp[kp * 1024 + col] = packf16(v0, v1);
  } else if (idx < 589824){
    int i = idx - 524288;
    int col = i >> 8, kp = i & 255;
    Wcp[kp * 256 + col] = packf16(Wc[col * 512 + 2 * kp], Wc[col * 512 + 2 * kp + 1]);
  } else if (idx < 590848){
    int i = idx - 589824;
    bA[i] = bih_r[i] + bhh_r[i];
  } else if (idx < 591872){
    int i = idx - 590848;
    bE[i] = bih_w[i] + bhh_w[i];
  } else if (idx < 592128){
    int i = idx - 591872;
    bcf[i] = bc[i];
  } else if (idx < 592384){
    int c = idx - 592128;
    float s = 0.f;
    for (int k = 0; k < 256; k++) s += Wc[c * 512 + 256 + k];
    wcs[c] = s;
  } else if (idx < 723456){
    int l = idx - 592384;
    unsigned char mv;
    if      (mode == 0) mv = (((const int*)maskraw)[l] != 0);
    else if (mode == 1) mv = (maskraw[l] != 0);
    else if (mode == 2) mv = ((maskraw[2*l] | maskraw[2*l+1]) != 0);
    else                mv = (((const unsigned int*)maskraw)[l] != 0);
    mbuf[l] = mv;
  } else if (idx < 724224){
    flags[idx - 723456] = 0;   // fR 128 | (unused 64) | fG 64 | fW 64 | fT0 256
  }
}

// ---- k_pre: gxp[t][b][cp] = packed f16 pairs of (emb[t,b,:] @ Wih_r^T) ------
__global__ __launch_bounds__(1024) void k_pre(
        const float* __restrict__ emb, const u32* __restrict__ WAp,
        u32* __restrict__ gxp){
  __shared__ u32 wt[16384];          // [kp 128][c 128]
  __shared__ u32 xt[128 * 129];      // [b][kp] padded
  int t = blockIdx.x, c0 = blockIdx.y * 128, tid = threadIdx.x;
  for (int i = 0; i < 16; i++){
    int idx = i * 1024 + tid;
    wt[idx] = WAp[(size_t)(idx >> 7) * 1024 + c0 + (idx & 127)];
    int b = idx >> 7, kp = idx & 127;
    float2 e2 = *(const float2*)(emb + (size_t)t * 32768 + b * 256 + 2 * kp);
    xt[b * 129 + kp] = packf16(e2.x, e2.y);
  }
  __syncthreads();
  int b = tid & 127, cg = tid >> 7;
  float acc[16];
  #pragma unroll
  for (int j = 0; j < 16; j++) acc[j] = 0.f;
  const u32* xrow = xt + b * 129;
  for (int kp = 0; kp < 128; kp++){
    u32 xv = xrow[kp];
    const uint4* wr = (const uint4*)(wt + kp * 128 + cg * 16);
    #pragma unroll
    for (int j4 = 0; j4 < 4; j4++){
      uint4 wv = wr[j4];
      acc[4*j4+0] = dot2u(wv.x, xv, acc[4*j4+0]);
      acc[4*j4+1] = dot2u(wv.y, xv, acc[4*j4+1]);
      acc[4*j4+2] = dot2u(wv.z, xv, acc[4*j4+2]);
      acc[4*j4+3] = dot2u(wv.w, xv, acc[4*j4+3]);
    }
  }
  u32* gp = gxp + ((size_t)t * 128 + b) * 512 + (c0 >> 1) + cg * 8;
  #pragma unroll
  for (int i = 0; i < 8; i++) gp[i] = packf16(acc[2*i], acc[2*i+1]);
}

// gemv: 1024 cols, K=256 (128 half2 rows). thread = (cg: 4 cols, ks: 4 slices)
__device__ __forceinline__ void gemv256(const u32* __restrict__ W,
        const u32* xh, float* psum, int tid){
  int cg = tid & 255, ks = tid >> 8;
  const uint4* wp = (const uint4*)W + (size_t)ks * 32 * 256 + cg;
  const u32* xk = xh + ks * 32;
  float a0 = 0.f, a1 = 0.f, a2 = 0.f, a3 = 0.f;
  #pragma unroll 8
  for (int i = 0; i < 32; i++){
    uint4 wv = wp[(size_t)i * 256];
    u32 xp = xk[i];
    a0 = dot2u(wv.x, xp, a0);  a1 = dot2u(wv.y, xp, a1);
    a2 = dot2u(wv.z, xp, a2);  a3 = dot2u(wv.w, xp, a3);
  }
  float4 r; r.x = a0; r.y = a1; r.z = a2; r.w = a3;
  *(float4*)&psum[ks * 1024 + cg * 4] = r;
}

// gemv: 256 cols, K=128 half2 rows. thread = (c: 1 col, ks: 4 slices of 32)
__device__ __forceinline__ void gemv128x256(const u32* __restrict__ W,
        const u32* xh, float* psum, int tid){
  int c = tid & 255, ks = tid >> 8;
  const u32* wp = W + (size_t)(ks * 32) * 256 + c;
  const u32* xk = xh + ks * 32;
  float a = 0.f;
  #pragma unroll 8
  for (int i = 0; i < 32; i++) a = dot2u(wp[(size_t)i * 256], xk[i], a);
  psum[ks * 256 + c] = a;
}

// ---- distributed t=0 flash scan: block k scans row k>>1, half k&1 (512 l) ---
__device__ void scan_half(int k, const float* __restrict__ M0,
        const unsigned char* __restrict__ mbuf, const float* __restrict__ hrf,
        float* spbuf, float* mpbuf, float* msbuf, u32* fT0, const u32* fR,
        char* sc, int tid){
  float* ps   = (float*)(sc);            // [16][260]
  float* wred = (float*)(sc + 16640);    // [16]
  float* sred = (float*)(sc + 16704);    // [16]
  float* hr0l = (float*)(sc + 16768);    // [256]
  int row = k >> 1, half = k & 1;
  pollk(fR + row, 1, 1u, tid);
  if (tid < 256) hr0l[tid] = alf(hrf + row * 256 + tid);   // slot 0
  __syncthreads();
  int w = tid >> 6, lane = tid & 63;
  float4 hrv = *(const float4*)&hr0l[lane * 4];
  float run_max = -INFINITY, S = 0.f;
  float m0 = 0.f, m1 = 0.f, m2 = 0.f, m3 = 0.f;
  int l0 = half * 512 + w * 32;
  for (int l = l0; l < l0 + 32; ++l){
    float4 Mv = *(const float4*)(M0 + ((size_t)row * 1024 + l) * 256 + lane * 4);
    float part = Mv.x * hrv.x + Mv.y * hrv.y + Mv.z * hrv.z + Mv.w * hrv.w;
    #pragma unroll
    for (int mm = 32; mm >= 1; mm >>= 1) part += __shfl_xor(part, mm, 64);
    float s = mbuf[row * 1024 + l] ? -INFINITY : part;
    if (lane == 0) asf(spbuf + row * 1024 + l, s);
    float nm = fmaxf(run_max, s);
    if (nm > -INFINITY){
      float sc2 = expf(run_max - nm);
      float p   = expf(s - nm);
      S = S * sc2 + p;
      m0 = m0 * sc2 + p * Mv.x;  m1 = m1 * sc2 + p * Mv.y;
      m2 = m2 * sc2 + p * Mv.z;  m3 = m3 * sc2 + p * Mv.w;
      run_max = nm;
    }
  }
  if (lane == 0){ wred[w] = run_max; sred[w] = S; }
  ps[w * 260 + lane * 4 + 0] = m0;
  ps[w * 260 + lane * 4 + 1] = m1;
  ps[w * 260 + lane * 4 + 2] = m2;
  ps[w * 260 + lane * 4 + 3] = m3;
  __syncthreads();
  float gmax = -INFINITY;
  #pragma unroll
  for (int w2 = 0; w2 < 16; w2++) gmax = fmaxf(gmax, wred[w2]);
  float Sg = 0.f;
  #pragma unroll
  for (int w2 = 0; w2 < 16; w2++) Sg += sred[w2] * expf(wred[w2] - gmax);
  if (tid < 256){
    float mv = 0.f;
    #pragma unroll
    for (int w2 = 0; w2 < 16; w2++) mv += ps[w2 * 260 + tid] * expf(wred[w2] - gmax);
    asf(mpbuf + k * 256 + tid, mv);     // unnormalized, relative to gmax
  }
  if (tid == 0){ asf(msbuf + 2 * k, gmax); asf(msbuf + 2 * k + 1, Sg); }
  __syncthreads();   // drains all prior stores
  if (tid == 0) asu(fT0 + k, 1u);
}

// ---- main: 256 persistent blocks, 1 per CU GUARANTEED (LDS 84KB > 160/2).
// R [0,128):   row b: hr-chain (gxp + Whh_r) + u = Wc_hr@hr. 2-slot buffers.
// G [128,192): rows 2g,2g+1: gw = Whh_w@hw(t-1) only.
// W [192,256): rows 2g,2g+1: 2-round z-update (gm=max(S1,S2), Ab=1-Cb),
//              e = u+Ab*wcs+Cb*vc+bc with vc computed LOCALLY at prev tail,
//              softmax, Wih_w@pe, combine with gw, nonlinearity.
//              hr/u prefetched at tail (poll fR>=t+2, hidden under vc gemv).
__global__ __launch_bounds__(1024, 4) void k_main(
        const float* __restrict__ hr0, const float* __restrict__ cr0,
        const float* __restrict__ hw0, const float* __restrict__ cw0,
        const float* __restrict__ M0,
        const u32* __restrict__ WAp, const u32* __restrict__ WEp,
        const u32* __restrict__ Wcp, const float* __restrict__ bA,
        const float* __restrict__ bE, const float* __restrict__ bcf,
        const float* __restrict__ wcs, const unsigned char* __restrict__ mbuf,
        const u32* __restrict__ gxp,
        float* __restrict__ hrf, float* __restrict__ ubuf,
        float* __restrict__ gwbuf,
        u32* __restrict__ hwp, float* __restrict__ zsbuf,
        float* __restrict__ hwfin, float* __restrict__ spbuf,
        float* __restrict__ mpbuf, float* __restrict__ msbuf,
        u32* __restrict__ flags, float* __restrict__ out){
  // 84KB static LDS: forces exactly 1 block/CU -> grid 256 == CU count,
  // all persistent blocks provably co-resident (no spin-wait deadlock).
  __shared__ __attribute__((aligned(16))) char smem[86016];
  int bid = blockIdx.x, tid = threadIdx.x;
  int w = tid >> 6, lane = tid & 63;
  u32* fR  = flags;          // 128
  u32* fG  = flags + 192;    // 64
  u32* fW  = flags + 256;    // 64
  u32* fT0 = flags + 320;    // 256

  if (bid < 128){
    // ===================== R: read-LSTM + u-gemv =====================
    int b = bid;
    float* psum = (float*)(smem);            // 16KB
    u32*  xh    = (u32*)(smem + 16384);      // 512B
    float* hr_f = (float*)(smem + 16896);    // 1KB
    const u32* WRh = WAp + 128 * 1024;       // Whh_r half
    float cst = (tid < 256) ? cr0[b * 256 + tid] : 0.f;
    if (tid < 128){
      float2 h0 = *(const float2*)(hr0 + b * 256 + 2 * tid);
      xh[tid] = packf16(h0.x, h0.y);
    }
    __syncthreads();
    for (int t = 0; t < kT; t++){
      if (t >= 2) pollk(fW + (b >> 1), 1, (u32)(t - 1), tid);  // 2-slot bp
      u32 gx0 = 0, gx1 = 0, gx2 = 0, gx3 = 0;
      if (tid < 256){
        const u32* gx = gxp + ((size_t)t * 128 + b) * 512;
        gx0 = gx[tid >> 1];          gx1 = gx[128 + (tid >> 1)];
        gx2 = gx[256 + (tid >> 1)];  gx3 = gx[384 + (tid >> 1)];
      }
      gemv256(WRh, xh, psum, tid);
      __syncthreads();
      if (tid < 256){
        H2U p0, p1, p2, p3;
        p0.u = gx0; p1.u = gx1; p2.u = gx2; p3.u = gx3;
        int hi = tid & 1;
        float gi = (hi ? (float)p0.h.y : (float)p0.h.x) + bA[tid];
        float gf = (hi ? (float)p1.h.y : (float)p1.h.x) + bA[256 + tid];
        float gg = (hi ? (float)p2.h.y : (float)p2.h.x) + bA[512 + tid];
        float go = (hi ? (float)p3.h.y : (float)p3.h.x) + bA[768 + tid];
        #pragma unroll
        for (int ks = 0; ks < 4; ks++){
          gi += psum[ks * 1024 + tid];
          gf += psum[ks * 1024 + 256 + tid];
          gg += psum[ks * 1024 + 512 + tid];
          go += psum[ks * 1024 + 768 + tid];
        }
        float i_ = 1.f / (1.f + expf(-gi));
        float f_ = 1.f / (1.f + expf(-gf));
        float g_ = tanhf(gg);
        float o_ = 1.f / (1.f + expf(-go));
        float c2 = f_ * cst + i_ * g_;
        cst = c2;
        float h = o_ * tanhf(c2);
        hr_f[tid] = h;
        asf(hrf + (t & 1) * 32768 + b * 256 + tid, h);
        if (t == kT - 1){
          out[OUT_STATES          + b * 256 + tid] = h;
          out[OUT_STATES +  32768 + b * 256 + tid] = c2;
        }
      }
      __syncthreads();
      if (tid < 128) xh[tid] = packf16(hr_f[2 * tid], hr_f[2 * tid + 1]);
      __syncthreads();
      gemv128x256(Wcp, xh, psum, tid);     // u = Wc_hr @ hr_t
      __syncthreads();
      if (tid < 256){
        float u = psum[tid] + psum[256 + tid] + psum[512 + tid] + psum[768 + tid];
        asf(ubuf + (t & 1) * 32768 + b * 256 + tid, u);
      }
      __syncthreads();   // drain before flag
      if (tid == 0) asu(fR + b, (u32)(t + 1));
      if (t == 0)
        scan_half(bid, M0, mbuf, hrf, spbuf, mpbuf, msbuf, fT0, fR,
                  smem + 49152, tid);
    }
  } else if (bid < 192){
    // ===================== G: gw gemv only (2 rows) =====================
    int g = bid - 128, r0 = 2 * g, r1 = 2 * g + 1;
    float* psum = (float*)(smem);            // 32KB
    u32*  xh    = (u32*)(smem + 32768);      // 1KB
    for (int t = 0; t < kT; t++){
      if (t == 0){
        if (tid < 128){
          float2 h0 = *(const float2*)(hw0 + r0 * 256 + 2 * tid);
          xh[tid] = packf16(h0.x, h0.y);
        } else if (tid < 256){
          int j = tid - 128;
          float2 h0 = *(const float2*)(hw0 + r1 * 256 + 2 * j);
          xh[tid] = packf16(h0.x, h0.y);
        }
      } else {
        pollk(fW + g, 1, (u32)t, tid);
        if (tid < 128)
          xh[tid] = alu(hwp + ((t - 1) & 1) * 16384 + r0 * 128 + tid);
        else if (tid < 256)
          xh[tid] = alu(hwp + ((t - 1) & 1) * 16384 + r1 * 128 + (tid - 128));
      }
      __syncthreads();
      {  // gw = Whh_w @ hw(t-1), both rows
        int cg = tid & 255, ks = tid >> 8;
        const uint4* wp = (const uint4*)(WEp + 128 * 1024)
                        + (size_t)(ks * 32) * 256 + cg;
        const u32* x0 = xh + ks * 32;
        const u32* x1 = xh + 128 + ks * 32;
        float a0=0.f,a1=0.f,a2=0.f,a3=0.f,b0=0.f,b1=0.f,b2=0.f,b3=0.f;
        #pragma unroll 4
        for (int ii = 0; ii < 32; ii++){
          uint4 wv = wp[(size_t)ii * 256];
          u32 xp0 = x0[ii], xp1 = x1[ii];
          a0 = dot2u(wv.x, xp0, a0);  a1 = dot2u(wv.y, xp0, a1);
          a2 = dot2u(wv.z, xp0, a2);  a3 = dot2u(wv.w, xp0, a3);
          b0 = dot2u(wv.x, xp1, b0);  b1 = dot2u(wv.y, xp1, b1);
          b2 = dot2u(wv.z, xp1, b2);  b3 = dot2u(wv.w, xp1, b3);
        }
        float4 ra; ra.x=a0; ra.y=a1; ra.z=a2; ra.w=a3;
        float4 rb; rb.x=b0; rb.y=b1; rb.z=b2; rb.w=b3;
        *(float4*)&psum[ks * 1024 + cg * 4] = ra;
        *(float4*)&psum[4096 + ks * 1024 + cg * 4] = rb;
      }
      __syncthreads();
      #pragma unroll
      for (int rr = 0; rr < 2; rr++){
        float v = psum[rr * 4096 + tid] + psum[rr * 4096 + 1024 + tid]
                + psum[rr * 4096 + 2048 + tid] + psum[rr * 4096 + 3072 + tid];
        asf(gwbuf + (t & 1) * 131072 + (2 * g + rr) * 1024 + tid, v);
      }
      __syncthreads();   // drain before flag
      if (tid == 0) asu(fG + g, (u32)(t + 1));
      if (t == 0)
        scan_half(bid, M0, mbuf, hrf, spbuf, mpbuf, msbuf, fT0, fR,
                  smem + 49152, tid);
    }
  } else {
    // ===================== W: z + comp + write-LSTM (2 rows) ==================
    int g = bid - 192, r0g = 2 * g;
    float* psum  = (float*)(smem);           // 32KB [2][4][1024]
    u32*  xh    = (u32*)(smem + 32768);      // 1KB
    float* comp  = (float*)(smem + 33792);   // [2][256]
    float* hw_f  = (float*)(smem + 35840);   // [2][256]
    float* m_f   = (float*)(smem + 37888);   // [2][256]
    float* wcs_l = (float*)(smem + 39936);   // [256]
    float* bc_l  = (float*)(smem + 40960);   // [256]
    float* redA  = (float*)(smem + 41984);   // [16]
    float* redB  = (float*)(smem + 42048);
    float* redC  = (float*)(smem + 42112);
    float* redD  = (float*)(smem + 42176);
    float* bE_l  = (float*)(smem + 43008);   // [1024]
    int row = tid >> 9, i = tid & 511;
    int brow = r0g + row;
    if (tid < 256){ wcs_l[tid] = wcs[tid]; bc_l[tid] = bcf[tid]; }
    bE_l[tid] = bE[tid];
    float cst = 0.f;
    if (i < 256){
      hw_f[row * 256 + i] = hw0[brow * 256 + i];
      cst = cw0[brow * 256 + i];
    }
    unsigned char mkA = mbuf[brow * 1024 + i];
    unsigned char mkB = mbuf[brow * 1024 + 512 + i];
    float zA = 0.f, zB = 0.f, vcreg = 0.f;
    __syncthreads();
    // scan duty first (publishes partials other W blocks need)
    scan_half(bid, M0, mbuf, hrf, spbuf, mpbuf, msbuf, fT0, fR,
              smem + 49152, tid);
    // prefetch step-0 hr/u (slot 0)
    pollk(fR + r0g, 2, 1u, tid);
    float hrv = 0.f, ureg = 0.f;
    if (i < 256){
      hrv  = alf(hrf + brow * 256 + i);
      ureg = alf(ubuf + brow * 256 + i);
    }

    for (int t = 0; t < kT; t++){
      float e = -INFINITY;
      if (t == 0){
        pollk(fT0 + 4 * g, 4, 1u, tid);
        int kA2 = 2 * brow, kB2 = 2 * brow + 1;
        float maxA = alf(msbuf + 2 * kA2), SAv = alf(msbuf + 2 * kA2 + 1);
        float maxB = alf(msbuf + 2 * kB2), SBv = alf(msbuf + 2 * kB2 + 1);
        float Gm = fmaxf(maxA, maxB);
        float eAc = expf(maxA - Gm), eBc = expf(maxB - Gm);
        float Sg = SAv * eAc + SBv * eBc;
        zA = expf(alf(spbuf + brow * 1024 + i) - Gm) / Sg;
        zB = expf(alf(spbuf + brow * 1024 + 512 + i) - Gm) / Sg;
        if (i < 256){
          float mv = (alf(mpbuf + kA2 * 256 + i) * eAc
                    + alf(mpbuf + kB2 * 256 + i) * eBc) / Sg;
          m_f[row * 256 + i] = mv;
        }
        __syncthreads();
        if (i < 128)
          xh[row * 128 + i] = packf16(m_f[row * 256 + 2 * i],
                                      m_f[row * 256 + 2 * i + 1]);
        __syncthreads();
        {  // vcm = Wc_m @ m0, both rows (one-time)
          int c = tid & 255, ks = tid >> 8;
          const u32* wp = Wcp + 32768 + (size_t)(ks * 32) * 256 + c;
          const u32* x0 = xh + ks * 32;
          const u32* x1 = xh + 128 + ks * 32;
          float a0 = 0.f, a1 = 0.f;
          #pragma unroll 8
          for (int ii = 0; ii < 32; ii++){
            u32 wv = wp[(size_t)ii * 256];
            a0 = dot2u(wv, x0[ii], a0);
            a1 = dot2u(wv, x1[ii], a1);
          }
          psum[ks * 512 + c] = a0;
          psum[ks * 512 + 256 + c] = a1;
        }
        __syncthreads();
        if (i < 256){
          float vcm = psum[row * 256 + i] + psum[512 + row * 256 + i]
                    + psum[1024 + row * 256 + i] + psum[1536 + row * 256 + i];
          e = ureg + vcm + bc_l[i];
        }
      } else {
        // 2-round z-update: s is a convex combination of S1,S2 (z in [0,1]),
        // so gm = max(S1,S2) is a valid exp-shift bound; Ab = 1-Cb (sum zn = 1).
        float v1 = (i < 256) ? hrv : 0.f;
        float v2 = (i < 256) ? hrv * hw_f[row * 256 + i] : 0.f;
        #pragma unroll
        for (int mm = 32; mm >= 1; mm >>= 1){
          v1 += __shfl_xor(v1, mm, 64);  v2 += __shfl_xor(v2, mm, 64);
        }
        if (lane == 0){ redA[w] = v1; redB[w] = v2; }
        __syncthreads();
        float S1 = 0.f, S2 = 0.f;
        #pragma unroll
        for (int k2 = 0; k2 < 8; k2++){
          S1 += redA[row * 8 + k2];  S2 += redB[row * 8 + k2];
        }
        float gm = fmaxf(S1, S2);
        float sA = mkA ? -INFINITY : (1.f - zA) * S1 + zA * S2;
        float sB = mkB ? -INFINITY : (1.f - zB) * S1 + zB * S2;
        float pA_ = expf(sA - gm), pB_ = expf(sB - gm);
        float ps = pA_ + pB_, pz = pA_ * zA + pB_ * zB;
        #pragma unroll
        for (int mm = 32; mm >= 1; mm >>= 1){
          ps += __shfl_xor(ps, mm, 64);  pz += __shfl_xor(pz, mm, 64);
        }
        if (lane == 0){ redC[w] = ps; redD[w] = pz; }
        __syncthreads();
        float Ss = 0.f, Pz = 0.f;
        #pragma unroll
        for (int k2 = 0; k2 < 8; k2++){
          Ss += redC[row * 8 + k2];  Pz += redD[row * 8 + k2];
        }
        float Cb = Pz / Ss, Ab = 1.f - Cb;
        zA = pA_ / Ss;  zB = pB_ / Ss;
        if (i < 256)
          e = ureg + Ab * wcs_l[i] + Cb * vcreg + bc_l[i];   // vc local (tail)
      }
      // softmax over 256 per row (true max; pe unnormalized)
      float ev = (i < 256) ? e : -INFINITY;
      float mx2 = ev;
      #pragma unroll
      for (int mm = 32; mm >= 1; mm >>= 1) mx2 = fmaxf(mx2, __shfl_xor(mx2, mm, 64));
      if (lane == 0) redC[w] = mx2;
      __syncthreads();
      float emax = -INFINITY;
      #pragma unroll
      for (int k2 = 0; k2 < 8; k2++) emax = fmaxf(emax, redC[row * 8 + k2]);
      float pe = (i < 256) ? expf(ev - emax) : 0.f;
      float ps2 = pe;
      #pragma unroll
      for (int mm = 32; mm >= 1; mm >>= 1) ps2 += __shfl_xor(ps2, mm, 64);
      if (lane == 0) redD[w] = ps2;
      if (i < 256) comp[row * 256 + i] = pe;
      __syncthreads();
      float esum = 0.f;
      #pragma unroll
      for (int k2 = 0; k2 < 8; k2++) esum += redD[row * 8 + k2];
      if (i < 128)
        xh[row * 128 + i] = packf16(comp[row * 256 + 2 * i],
                                    comp[row * 256 + 2 * i + 1]);
      __syncthreads();
      {  // Wih_w @ pe, both rows
        int cg = tid & 255, ks = tid >> 8;
        const uint4* wp = (const uint4*)WEp + (size_t)(ks * 32) * 256 + cg;
        const u32* x0 = xh + ks * 32;
        const u32* x1 = xh + 128 + ks * 32;
        float a0=0.f,a1=0.f,a2=0.f,a3=0.f,b0=0.f,b1=0.f,b2=0.f,b3=0.f;
        #pragma unroll 4
        for (int ii = 0; ii < 32; ii++){
          uint4 wv = wp[(size_t)ii * 256];
          u32 xp0 = x0[ii], xp1 = x1[ii];
          a0 = dot2u(wv.x, xp0, a0);  a1 = dot2u(wv.y, xp0, a1);
          a2 = dot2u(wv.z, xp0, a2);  a3 = dot2u(wv.w, xp0, a3);
          b0 = dot2u(wv.x, xp1, b0);  b1 = dot2u(wv.y, xp1, b1);
          b2 = dot2u(wv.z, xp1, b2);  b3 = dot2u(wv.w, xp1, b3);
        }
        float4 ra; ra.x=a0; ra.y=a1; ra.z=a2; ra.w=a3;
        float4 rb; rb.x=b0; rb.y=b1; rb.z=b2; rb.w=b3;
        *(float4*)&psum[ks * 1024 + cg * 4] = ra;
        *(float4*)&psum[4096 + ks * 1024 + cg * 4] = rb;
      }
      __syncthreads();
      pollk(fG + g, 1, (u32)(t + 1), tid);
      if (i < 256){
        float rinv = 1.f / esum;
        const float* gwp = gwbuf + (t & 1) * 131072 + brow * 1024;
        float si = psum[row*4096 + i]        + psum[row*4096 + 1024 + i]
                 + psum[row*4096 + 2048 + i] + psum[row*4096 + 3072 + i];
        float sf = psum[row*4096 + 256 + i]  + psum[row*4096 + 1280 + i]
                 + psum[row*4096 + 2304 + i] + psum[row*4096 + 3328 + i];
        float sg2= psum[row*4096 + 512 + i]  + psum[row*4096 + 1536 + i]
                 + psum[row*4096 + 2560 + i] + psum[row*4096 + 3584 + i];
        float so = psum[row*4096 + 768 + i]  + psum[row*4096 + 1792 + i]
                 + psum[row*4096 + 2816 + i] + psum[row*4096 + 3840 + i];
        float gi = bE_l[i]       + alf(gwp + i)       + si  * rinv;
        float gf = bE_l[256 + i] + alf(gwp + 256 + i) + sf  * rinv;
        float gg = bE_l[512 + i] + alf(gwp + 512 + i) + sg2 * rinv;
        float go = bE_l[768 + i] + alf(gwp + 768 + i) + so  * rinv;
        float i_ = 1.f / (1.f + expf(-gi));
        float f_ = 1.f / (1.f + expf(-gf));
        float g_ = tanhf(gg);
        float o_ = 1.f / (1.f + expf(-go));
        float c2 = f_ * cst + i_ * g_;
        cst = c2;
        float h = o_ * tanhf(c2);
        hw_f[row * 256 + i] = h;
        out[(size_t)t * 32768 + brow * 256 + i] = h;
        if (t == kT - 1){
          out[OUT_STATES + 65536 + brow * 256 + i] = h;
          out[OUT_STATES + 98304 + brow * 256 + i] = c2;
        }
      }
      __syncthreads();
      if (i < 128)
        asu(hwp + (t & 1) * 16384 + brow * 128 + i,
            packf16(hw_f[row * 256 + 2 * i], hw_f[row * 256 + 2 * i + 1]));
      __syncthreads();   // drain before flag
      if (tid == 0) asu(fW + g, (u32)(t + 1));
      if (t < kT - 1){
        // tail: local vc = Wc_m @ hw(t) for next step's e; prefetch hr/u(t+1)
        // under the gemv (poll fR>=t+2 is instantly satisfied: R runs 2 ahead).
        if (i < 128)
          xh[row * 128 + i] = packf16(hw_f[row * 256 + 2 * i],
                                      hw_f[row * 256 + 2 * i + 1]);
        __syncthreads();
        pollk(fR + r0g, 2, (u32)(t + 2), tid);
        if (i < 256){
          hrv  = alf(hrf + ((t + 1) & 1) * 32768 + brow * 256 + i);
          ureg = alf(ubuf + ((t + 1) & 1) * 32768 + brow * 256 + i);
        }
        {
          int c = tid & 255, ks = tid >> 8;
          const u32* wp = Wcp + 32768 + (size_t)(ks * 32) * 256 + c;
          const u32* x0 = xh + ks * 32;
          const u32* x1 = xh + 128 + ks * 32;
          float a0 = 0.f, a1 = 0.f;
          #pragma unroll 8
          for (int ii = 0; ii < 32; ii++){
            u32 wv = wp[(size_t)ii * 256];
            a0 = dot2u(wv, x0[ii], a0);
            a1 = dot2u(wv, x1[ii], a1);
          }
          psum[ks * 512 + c] = a0;
          psum[ks * 512 + 256 + c] = a1;
        }
        __syncthreads();
        if (i < 256)
          vcreg = psum[row * 256 + i] + psum[512 + row * 256 + i]
                + psum[1024 + row * 256 + i] + psum[1536 + row * 256 + i];
        __syncthreads();
      }
    }
    // publish final z & hw for the M epilogue
    if (i < 256) asf(hwfin + brow * 256 + i, hw_f[row * 256 + i]);
    asf(zsbuf + brow * 1024 + i, zA);
    asf(zsbuf + brow * 1024 + 512 + i, zB);
    __syncthreads();   // drain before flag
    if (tid == 0) asu(fW + g, (u32)(kT + 1));
  }

  // ========== epilogue: every block writes half a row of M ==========
  {
    int mrow = bid >> 1, half = bid & 1;
    pollk(fW + (mrow >> 1), 1, (u32)(kT + 1), tid);
    float* zl  = (float*)(smem + 49152);   // [512]
    float* hwl = (float*)(smem + 51200);   // [256]
    if (tid < 512) zl[tid] = alf(zsbuf + mrow * 1024 + half * 512 + tid);
    else if (tid < 768) hwl[tid - 512] = alf(hwfin + mrow * 256 + (tid - 512));
    __syncthreads();
    float* Mout = out + OUT_M + (size_t)mrow * 262144 + (size_t)half * 131072;
    for (int it = 0; it < 32; it++){
      int idx = it * 1024 + tid;
      int l = idx >> 6, d4 = (idx & 63) << 2;
      float z = zl[l], omz = 1.f - z;
      float4 h4 = *(const float4*)&hwl[d4];
      float4 v;
      v.x = omz + h4.x * z;  v.y = omz + h4.y * z;
      v.z = omz + h4.z * z;  v.w = omz + h4.w * z;
      *(float4*)(Mout + (size_t)l * 256 + d4) = v;
    }
  }
}

extern "C" void kernel_launch(void* const* d_in, const int* in_sizes, int n_in,
                              void* d_out, int out_size, void* d_ws, size_t ws_size,
                              hipStream_t stream){
  const float* emb   = (const float*)d_in[0];
  const float* hr0   = (const float*)d_in[1];
  const float* cr0   = (const float*)d_in[2];
  const float* hw0   = (const float*)d_in[3];
  const float* cw0   = (const float*)d_in[4];
  const float* M0    = (const float*)d_in[5];
  const unsigned char* maskraw = (const unsigned char*)d_in[6];
  const float* Wih_r = (const float*)d_in[7];
  const float* Whh_r = (const float*)d_in[8];
  const float* bih_r = (const float*)d_in[9];
  const float* bhh_r = (const float*)d_in[10];
  const float* Wc    = (const float*)d_in[11];
  const float* bc    = (const float*)d_in[12];
  const float* Wih_w = (const float*)d_in[13];
  const float* Whh_w = (const float*)d_in[14];
  const float* bih_w = (const float*)d_in[15];
  const float* bhh_w = (const float*)d_in[16];
  float* out = (float*)d_out;

  char* ws = (char*)d_ws;
  u32*  WAp   = (u32*)(ws);                       // 1 MB
  u32*  WEp   = (u32*)(ws + 1048576);             // 1 MB
  u32*  Wcp   = (u32*)(ws + 2097152);             // 256 KB
  float* bA   = (float*)(ws + 2359296);           // 4 KB
  float* bE   = (float*)(ws + 2363392);           // 4 KB
  float* bcf  = (float*)(ws + 2367488);           // 1 KB
  float* wcs  = (float*)(ws + 2368512);           // 1 KB
  unsigned char* mbuf = (unsigned char*)(ws + 2369536);  // 128 KB
  u32*  flags = (u32*)(ws + 2500608);             // 4 KB (768 zeroed)
  float* hrf  = (float*)(ws + 2504704);           // 256 KB (2 slots)
  float* ubuf = (float*)(ws + 2766848);           // 256 KB
  float* gwbuf= (float*)(ws + 3291136);           // 1 MB (2 slots)
  u32*  hwp   = (u32*)(ws + 4339712);             // 128 KB
  float* zsbuf= (float*)(ws + 4470784);           // 512 KB
  float* hwfin= (float*)(ws + 4995072);           // 128 KB
  float* spbuf= (float*)(ws + 5126144);           // 512 KB (raw t0 scores)
  float* mpbuf= (float*)(ws + 5650432);           // 256 KB (t0 partial m)
  float* msbuf= (float*)(ws + 5912576);           // 2 KB   (t0 {max,S})
  u32*  gxp   = (u32*)(ws + 5914624);             // 8 MB

  k_prep<<<dim3(708), dim3(1024), 0, stream>>>(
      Wih_r, Whh_r, bih_r, bhh_r, Wc, bc, Wih_w, Whh_w, bih_w, bhh_w,
      maskraw, WAp, WEp, Wcp, bA, bE, bcf, wcs, mbuf, flags);
  k_pre<<<dim3(32, 8), dim3(1024), 0, stream>>>(emb, WAp, gxp);
  k_main<<<dim3(256), dim3(1024), 0, stream>>>(
      hr0, cr0, hw0, cw0, M0, WAp, WEp, Wcp, bA, bE, bcf, wcs, mbuf, gxp,
      hrf, ubuf, gwbuf, hwp, zsbuf, hwfin, spbuf, mpbuf, msbuf,
      flags, out);
}

// Round 9
// 635.303 us; speedup vs baseline: 1.0735x; 1.0305x over previous
//
#include <hip/hip_runtime.h>
#include <math.h>

typedef unsigned int u32;
typedef __attribute__((ext_vector_type(2))) _Float16 h2;

#define kT 32
#define OUT_STATES 1048576   // T*B*D
#define OUT_M      1179648   // + 4*B*D

union H2U { u32 u; h2 h; };

__device__ __forceinline__ float dot2u(u32 w, u32 x, float acc){
  H2U a; a.u = w; H2U b; b.u = x;
#if __has_builtin(__builtin_amdgcn_fdot2)
  return __builtin_amdgcn_fdot2(a.h, b.h, acc, false);
#else
  acc += (float)a.h.x * (float)b.h.x;
  acc += (float)a.h.y * (float)b.h.y;
  return acc;
#endif
}

__device__ __forceinline__ u32 packf16(float x, float y){
  H2U v; v.h.x = (_Float16)x; v.h.y = (_Float16)y; return v.u;
}

__device__ __forceinline__ u32 alu(const u32* p){
  return __hip_atomic_load((u32*)p, __ATOMIC_RELAXED, __HIP_MEMORY_SCOPE_AGENT);
}
__device__ __forceinline__ float alf(const float* p){
  return __hip_atomic_load((float*)p, __ATOMIC_RELAXED, __HIP_MEMORY_SCOPE_AGENT);
}
__device__ __forceinline__ void asu(u32* p, u32 v){
  __hip_atomic_store(p, v, __ATOMIC_RELAXED, __HIP_MEMORY_SCOPE_AGENT);
}
__device__ __forceinline__ void asf(float* p, float v){
  __hip_atomic_store(p, v, __ATOMIC_RELAXED, __HIP_MEMORY_SCOPE_AGENT);
}

// wave 0 polls n flags (n<=64), then block barrier
__device__ __forceinline__ void pollk(const u32* f, int n, u32 tgt, int tid){
  if (tid < 64){
    const u32* p = f + ((tid < n) ? tid : 0);
    for (;;){
      if (__all((int)(alu(p) >= tgt))) break;
      __builtin_amdgcn_s_sleep(2);
    }
  }
  __syncthreads();
}

// ---- prep: weights -> packed f16 [k/2][col] layout (coalesced source reads),
//      biases summed, wcs, mask, flags zeroed.
__global__ __launch_bounds__(1024) void k_prep(
        const float* __restrict__ Wih_r, const float* __restrict__ Whh_r,
        const float* __restrict__ bih_r, const float* __restrict__ bhh_r,
        const float* __restrict__ Wc,    const float* __restrict__ bc,
        const float* __restrict__ Wih_w, const float* __restrict__ Whh_w,
        const float* __restrict__ bih_w, const float* __restrict__ bhh_w,
        const unsigned char* __restrict__ maskraw,
        u32* WAp, u32* WEp, u32* Wcp, float* bA, float* bE, float* bcf,
        float* wcs, unsigned char* mbuf, u32* flags){
  __shared__ int sb[3];
  if (threadIdx.x < 3) sb[threadIdx.x] = 0;
  __syncthreads();
  if (threadIdx.x < 512){
    unsigned char c = maskraw[threadIdx.x];
    if (c > 1u) atomicOr(&sb[0], 1);
    if ((threadIdx.x & 3) != 0 && c != 0) atomicOr(&sb[1], 1);
    if ((threadIdx.x & 3) == 1 && c == 0x3F) atomicOr(&sb[2], 1);
  }
  __syncthreads();
  int mode = (!sb[0]) ? (sb[1] ? 1 : 0) : (sb[2] ? 2 : 3);

  int idx = blockIdx.x * 1024 + threadIdx.x;
  if (idx < 262144){
    int col = idx >> 8, kp = idx & 255;      // consecutive threads -> consec k
    int k0 = 2 * kp;
    float v0 = (k0 < 256) ? Wih_r[col * 256 + k0] : Whh_r[col * 256 + k0 - 256];
    float v1 = (k0 < 256) ? Wih_r[col * 256 + k0 + 1]
                          : Whh_r[col * 256 + k0 + 1 - 256];
    WAp[kp * 1024 + col] = packf16(v0, v1);
  } else if (idx < 524288){
    int i = idx - 262144;
    int col = i >> 8, kp = i & 255;
    int k0 = 2 * kp;
    float v0 = (k0 < 256) ? Wih_w[col * 256 + k0] : Whh_w[col * 256 + k0 - 256];
    float v1 = (k0 < 256) ? Wih_w[col * 256 + k0 + 1]
                          : Whh_w[col * 256 + k0 + 1 - 256];
    WEp[kp * 1024 + col] = packf16(v0, v1);
  } else if (idx < 589824){
    int i = idx - 524288;
    int col = i >> 8, kp = i & 255;
    Wcp[kp * 256 + col] = packf16(Wc[col * 512 + 2 * kp], Wc[col * 512 + 2 * kp + 1]);
  } else if (idx < 590848){
    int i = idx - 589824;
    bA[i] = bih_r[i] + bhh_r[i];
  } else if (idx < 591872){
    int i = idx - 590848;
    bE[i] = bih_w[i] + bhh_w[i];
  } else if (idx < 592128){
    int i = idx - 591872;
    bcf[i] = bc[i];
  } else if (idx < 592384){
    int c = idx - 592128;
    float s = 0.f;
    for (int k = 0; k < 256; k++) s += Wc[c * 512 + 256 + k];
    wcs[c] = s;
  } else if (idx < 723456){
    int l = idx - 592384;
    unsigned char mv;
    if      (mode == 0) mv = (((const int*)maskraw)[l] != 0);
    else if (mode == 1) mv = (maskraw[l] != 0);
    else if (mode == 2) mv = ((maskraw[2*l] | maskraw[2*l+1]) != 0);
    else                mv = (((const unsigned int*)maskraw)[l] != 0);
    mbuf[l] = mv;
  } else if (idx < 724224){
    flags[idx - 723456] = 0;   // fR 128 | fGv 64 | fG 64 | fW 64 | fT0 256
  }
}

// ---- k_pre: gxp[t][b][cp] = packed f16 pairs of (emb[t,b,:] @ Wih_r^T) ------
__global__ __launch_bounds__(1024) void k_pre(
        const float* __restrict__ emb, const u32* __restrict__ WAp,
        u32* __restrict__ gxp){
  __shared__ u32 wt[16384];          // [kp 128][c 128]
  __shared__ u32 xt[128 * 129];      // [b][kp] padded
  int t = blockIdx.x, c0 = blockIdx.y * 128, tid = threadIdx.x;
  for (int i = 0; i < 16; i++){
    int idx = i * 1024 + tid;
    wt[idx] = WAp[(size_t)(idx >> 7) * 1024 + c0 + (idx & 127)];
    int b = idx >> 7, kp = idx & 127;
    float2 e2 = *(const float2*)(emb + (size_t)t * 32768 + b * 256 + 2 * kp);
    xt[b * 129 + kp] = packf16(e2.x, e2.y);
  }
  __syncthreads();
  int b = tid & 127, cg = tid >> 7;
  float acc[16];
  #pragma unroll
  for (int j = 0; j < 16; j++) acc[j] = 0.f;
  const u32* xrow = xt + b * 129;
  for (int kp = 0; kp < 128; kp++){
    u32 xv = xrow[kp];
    const uint4* wr = (const uint4*)(wt + kp * 128 + cg * 16);
    #pragma unroll
    for (int j4 = 0; j4 < 4; j4++){
      uint4 wv = wr[j4];
      acc[4*j4+0] = dot2u(wv.x, xv, acc[4*j4+0]);
      acc[4*j4+1] = dot2u(wv.y, xv, acc[4*j4+1]);
      acc[4*j4+2] = dot2u(wv.z, xv, acc[4*j4+2]);
      acc[4*j4+3] = dot2u(wv.w, xv, acc[4*j4+3]);
    }
  }
  u32* gp = gxp + ((size_t)t * 128 + b) * 512 + (c0 >> 1) + cg * 8;
  #pragma unroll
  for (int i = 0; i < 8; i++) gp[i] = packf16(acc[2*i], acc[2*i+1]);
}

// gemv: 1024 cols, K=256 (128 half2 rows). thread = (cg: 4 cols, ks: 4 slices)
__device__ __forceinline__ void gemv256(const u32* __restrict__ W,
        const u32* xh, float* psum, int tid){
  int cg = tid & 255, ks = tid >> 8;
  const uint4* wp = (const uint4*)W + (size_t)ks * 32 * 256 + cg;
  const u32* xk = xh + ks * 32;
  float a0 = 0.f, a1 = 0.f, a2 = 0.f, a3 = 0.f;
  #pragma unroll 8
  for (int i = 0; i < 32; i++){
    uint4 wv = wp[(size_t)i * 256];
    u32 xp = xk[i];
    a0 = dot2u(wv.x, xp, a0);  a1 = dot2u(wv.y, xp, a1);
    a2 = dot2u(wv.z, xp, a2);  a3 = dot2u(wv.w, xp, a3);
  }
  float4 r; r.x = a0; r.y = a1; r.z = a2; r.w = a3;
  *(float4*)&psum[ks * 1024 + cg * 4] = r;
}

// gemv: 256 cols, K=128 half2 rows. thread = (c: 1 col, ks: 4 slices of 32)
__device__ __forceinline__ void gemv128x256(const u32* __restrict__ W,
        const u32* xh, float* psum, int tid){
  int c = tid & 255, ks = tid >> 8;
  const u32* wp = W + (size_t)(ks * 32) * 256 + c;
  const u32* xk = xh + ks * 32;
  float a = 0.f;
  #pragma unroll 8
  for (int i = 0; i < 32; i++) a = dot2u(wp[(size_t)i * 256], xk[i], a);
  psum[ks * 256 + c] = a;
}

// ---- distributed t=0 flash scan: block k scans row k>>1, half k&1 (512 l) ---
__device__ void scan_half(int k, const float* __restrict__ M0,
        const unsigned char* __restrict__ mbuf, const float* __restrict__ hrf,
        float* spbuf, float* mpbuf, float* msbuf, u32* fT0, const u32* fR,
        char* sc, int tid){
  float* ps   = (float*)(sc);            // [16][260]
  float* wred = (float*)(sc + 16640);    // [16]
  float* sred = (float*)(sc + 16704);    // [16]
  float* hr0l = (float*)(sc + 16768);    // [256]
  int row = k >> 1, half = k & 1;
  pollk(fR + row, 1, 1u, tid);
  if (tid < 256) hr0l[tid] = alf(hrf + row * 256 + tid);   // slot 0
  __syncthreads();
  int w = tid >> 6, lane = tid & 63;
  float4 hrv = *(const float4*)&hr0l[lane * 4];
  float run_max = -INFINITY, S = 0.f;
  float m0 = 0.f, m1 = 0.f, m2 = 0.f, m3 = 0.f;
  int l0 = half * 512 + w * 32;
  for (int l = l0; l < l0 + 32; ++l){
    float4 Mv = *(const float4*)(M0 + ((size_t)row * 1024 + l) * 256 + lane * 4);
    float part = Mv.x * hrv.x + Mv.y * hrv.y + Mv.z * hrv.z + Mv.w * hrv.w;
    #pragma unroll
    for (int mm = 32; mm >= 1; mm >>= 1) part += __shfl_xor(part, mm, 64);
    float s = mbuf[row * 1024 + l] ? -INFINITY : part;
    if (lane == 0) asf(spbuf + row * 1024 + l, s);
    float nm = fmaxf(run_max, s);
    if (nm > -INFINITY){
      float sc2 = expf(run_max - nm);
      float p   = expf(s - nm);
      S = S * sc2 + p;
      m0 = m0 * sc2 + p * Mv.x;  m1 = m1 * sc2 + p * Mv.y;
      m2 = m2 * sc2 + p * Mv.z;  m3 = m3 * sc2 + p * Mv.w;
      run_max = nm;
    }
  }
  if (lane == 0){ wred[w] = run_max; sred[w] = S; }
  ps[w * 260 + lane * 4 + 0] = m0;
  ps[w * 260 + lane * 4 + 1] = m1;
  ps[w * 260 + lane * 4 + 2] = m2;
  ps[w * 260 + lane * 4 + 3] = m3;
  __syncthreads();
  float gmax = -INFINITY;
  #pragma unroll
  for (int w2 = 0; w2 < 16; w2++) gmax = fmaxf(gmax, wred[w2]);
  float Sg = 0.f;
  #pragma unroll
  for (int w2 = 0; w2 < 16; w2++) Sg += sred[w2] * expf(wred[w2] - gmax);
  if (tid < 256){
    float mv = 0.f;
    #pragma unroll
    for (int w2 = 0; w2 < 16; w2++) mv += ps[w2 * 260 + tid] * expf(wred[w2] - gmax);
    asf(mpbuf + k * 256 + tid, mv);     // unnormalized, relative to gmax
  }
  if (tid == 0){ asf(msbuf + 2 * k, gmax); asf(msbuf + 2 * k + 1, Sg); }
  __syncthreads();   // drains all prior stores
  if (tid == 0) asu(fT0 + k, 1u);
}

// ---- main: 256 persistent blocks, 1 per CU GUARANTEED (LDS 84KB > 160/2).
// R [0,128):   row b: hr-chain (gxp + Whh_r) + u = Wc_hr@hr. 2-slot buffers.
// G [128,192): rows 2g,2g+1: vc = Wc_m@hw(t-1) (early fGv flag), then gw.
// W [192,256): rows 2g,2g+1: 2-round z-update (gm=max(S1,S2), Ab=1-Cb),
//              e = u+Ab*wcs+Cb*vc+bc (vc from G), fixed-shift softmax
//              pe=exp(e-4) (exact after normalization), Wih_w@pe, combine,
//              nonlinearity. hr/u prefetched at tail (fR>=t+2 instant).
__global__ __launch_bounds__(1024, 4) void k_main(
        const float* __restrict__ hr0, const float* __restrict__ cr0,
        const float* __restrict__ hw0, const float* __restrict__ cw0,
        const float* __restrict__ M0,
        const u32* __restrict__ WAp, const u32* __restrict__ WEp,
        const u32* __restrict__ Wcp, const float* __restrict__ bA,
        const float* __restrict__ bE, const float* __restrict__ bcf,
        const float* __restrict__ wcs, const unsigned char* __restrict__ mbuf,
        const u32* __restrict__ gxp,
        float* __restrict__ hrf, float* __restrict__ ubuf,
        float* __restrict__ vcbuf, float* __restrict__ gwbuf,
        u32* __restrict__ hwp, float* __restrict__ zsbuf,
        float* __restrict__ hwfin, float* __restrict__ spbuf,
        float* __restrict__ mpbuf, float* __restrict__ msbuf,
        u32* __restrict__ flags, float* __restrict__ out){
  // 84KB static LDS: forces exactly 1 block/CU -> grid 256 == CU count,
  // all persistent blocks provably co-resident (no spin-wait deadlock).
  __shared__ __attribute__((aligned(16))) char smem[86016];
  int bid = blockIdx.x, tid = threadIdx.x;
  int w = tid >> 6, lane = tid & 63;
  u32* fR  = flags;          // 128
  u32* fGv = flags + 128;    // 64
  u32* fG  = flags + 192;    // 64
  u32* fW  = flags + 256;    // 64
  u32* fT0 = flags + 320;    // 256

  if (bid < 128){
    // ===================== R: read-LSTM + u-gemv =====================
    int b = bid;
    float* psum = (float*)(smem);            // 16KB
    u32*  xh    = (u32*)(smem + 16384);      // 512B
    float* hr_f = (float*)(smem + 16896);    // 1KB
    const u32* WRh = WAp + 128 * 1024;       // Whh_r half
    float cst = (tid < 256) ? cr0[b * 256 + tid] : 0.f;
    if (tid < 128){
      float2 h0 = *(const float2*)(hr0 + b * 256 + 2 * tid);
      xh[tid] = packf16(h0.x, h0.y);
    }
    __syncthreads();
    for (int t = 0; t < kT; t++){
      if (t >= 2) pollk(fW + (b >> 1), 1, (u32)(t - 1), tid);  // 2-slot bp
      u32 gx0 = 0, gx1 = 0, gx2 = 0, gx3 = 0;
      if (tid < 256){
        const u32* gx = gxp + ((size_t)t * 128 + b) * 512;
        gx0 = gx[tid >> 1];          gx1 = gx[128 + (tid >> 1)];
        gx2 = gx[256 + (tid >> 1)];  gx3 = gx[384 + (tid >> 1)];
      }
      gemv256(WRh, xh, psum, tid);
      __syncthreads();
      if (tid < 256){
        H2U p0, p1, p2, p3;
        p0.u = gx0; p1.u = gx1; p2.u = gx2; p3.u = gx3;
        int hi = tid & 1;
        float gi = (hi ? (float)p0.h.y : (float)p0.h.x) + bA[tid];
        float gf = (hi ? (float)p1.h.y : (float)p1.h.x) + bA[256 + tid];
        float gg = (hi ? (float)p2.h.y : (float)p2.h.x) + bA[512 + tid];
        float go = (hi ? (float)p3.h.y : (float)p3.h.x) + bA[768 + tid];
        #pragma unroll
        for (int ks = 0; ks < 4; ks++){
          gi += psum[ks * 1024 + tid];
          gf += psum[ks * 1024 + 256 + tid];
          gg += psum[ks * 1024 + 512 + tid];
          go += psum[ks * 1024 + 768 + tid];
        }
        float i_ = 1.f / (1.f + expf(-gi));
        float f_ = 1.f / (1.f + expf(-gf));
        float g_ = tanhf(gg);
        float o_ = 1.f / (1.f + expf(-go));
        float c2 = f_ * cst + i_ * g_;
        cst = c2;
        float h = o_ * tanhf(c2);
        hr_f[tid] = h;
        asf(hrf + (t & 1) * 32768 + b * 256 + tid, h);
        if (t == kT - 1){
          out[OUT_STATES          + b * 256 + tid] = h;
          out[OUT_STATES +  32768 + b * 256 + tid] = c2;
        }
      }
      __syncthreads();
      if (tid < 128) xh[tid] = packf16(hr_f[2 * tid], hr_f[2 * tid + 1]);
      __syncthreads();
      gemv128x256(Wcp, xh, psum, tid);     // u = Wc_hr @ hr_t
      __syncthreads();
      if (tid < 256){
        float u = psum[tid] + psum[256 + tid] + psum[512 + tid] + psum[768 + tid];
        asf(ubuf + (t & 1) * 32768 + b * 256 + tid, u);
      }
      __syncthreads();   // drain before flag
      if (tid == 0) asu(fR + b, (u32)(t + 1));
      if (t == 0)
        scan_half(bid, M0, mbuf, hrf, spbuf, mpbuf, msbuf, fT0, fR,
                  smem + 49152, tid);
    }
  } else if (bid < 192){
    // ===================== G: vc + gw gemvs (2 rows) =====================
    int g = bid - 128, r0 = 2 * g, r1 = 2 * g + 1;
    float* psum = (float*)(smem);            // 32KB
    u32*  xh    = (u32*)(smem + 32768);      // 1KB
    for (int t = 0; t < kT; t++){
      if (t == 0){
        if (tid < 128){
          float2 h0 = *(const float2*)(hw0 + r0 * 256 + 2 * tid);
          xh[tid] = packf16(h0.x, h0.y);
        } else if (tid < 256){
          int j = tid - 128;
          float2 h0 = *(const float2*)(hw0 + r1 * 256 + 2 * j);
          xh[tid] = packf16(h0.x, h0.y);
        }
      } else {
        pollk(fW + g, 1, (u32)t, tid);
        if (tid < 128)
          xh[tid] = alu(hwp + ((t - 1) & 1) * 16384 + r0 * 128 + tid);
        else if (tid < 256)
          xh[tid] = alu(hwp + ((t - 1) & 1) * 16384 + r1 * 128 + (tid - 128));
      }
      __syncthreads();
      // vc = Wc_m @ hw(t-1), both rows (published early for W's e)
      {
        int c = tid & 255, ks = tid >> 8;
        const u32* wp = Wcp + 32768 + (size_t)(ks * 32) * 256 + c;
        const u32* x0 = xh + ks * 32;
        const u32* x1 = xh + 128 + ks * 32;
        float a0 = 0.f, a1 = 0.f;
        #pragma unroll 8
        for (int ii = 0; ii < 32; ii++){
          u32 wv = wp[(size_t)ii * 256];
          a0 = dot2u(wv, x0[ii], a0);
          a1 = dot2u(wv, x1[ii], a1);
        }
        psum[ks * 512 + c] = a0;
        psum[ks * 512 + 256 + c] = a1;
      }
      __syncthreads();
      if (tid < 512){
        int rr = tid >> 8, c = tid & 255;
        float v = psum[rr * 256 + c] + psum[512 + rr * 256 + c]
                + psum[1024 + rr * 256 + c] + psum[1536 + rr * 256 + c];
        asf(vcbuf + (t & 1) * 32768 + (2 * g + rr) * 256 + c, v);
      }
      __syncthreads();   // drain before flag
      if (tid == 0) asu(fGv + g, (u32)(t + 1));
      {  // gw = Whh_w @ hw(t-1), both rows
        int cg = tid & 255, ks = tid >> 8;
        const uint4* wp = (const uint4*)(WEp + 128 * 1024)
                        + (size_t)(ks * 32) * 256 + cg;
        const u32* x0 = xh + ks * 32;
        const u32* x1 = xh + 128 + ks * 32;
        float a0=0.f,a1=0.f,a2=0.f,a3=0.f,b0=0.f,b1=0.f,b2=0.f,b3=0.f;
        #pragma unroll 4
        for (int ii = 0; ii < 32; ii++){
          uint4 wv = wp[(size_t)ii * 256];
          u32 xp0 = x0[ii], xp1 = x1[ii];
          a0 = dot2u(wv.x, xp0, a0);  a1 = dot2u(wv.y, xp0, a1);
          a2 = dot2u(wv.z, xp0, a2);  a3 = dot2u(wv.w, xp0, a3);
          b0 = dot2u(wv.x, xp1, b0);  b1 = dot2u(wv.y, xp1, b1);
          b2 = dot2u(wv.z, xp1, b2);  b3 = dot2u(wv.w, xp1, b3);
        }
        float4 ra; ra.x=a0; ra.y=a1; ra.z=a2; ra.w=a3;
        float4 rb; rb.x=b0; rb.y=b1; rb.z=b2; rb.w=b3;
        *(float4*)&psum[ks * 1024 + cg * 4] = ra;
        *(float4*)&psum[4096 + ks * 1024 + cg * 4] = rb;
      }
      __syncthreads();
      #pragma unroll
      for (int rr = 0; rr < 2; rr++){
        float v = psum[rr * 4096 + tid] + psum[rr * 4096 + 1024 + tid]
                + psum[rr * 4096 + 2048 + tid] + psum[rr * 4096 + 3072 + tid];
        asf(gwbuf + (t & 1) * 131072 + (2 * g + rr) * 1024 + tid, v);
      }
      __syncthreads();   // drain before flag
      if (tid == 0) asu(fG + g, (u32)(t + 1));
      if (t == 0)
        scan_half(bid, M0, mbuf, hrf, spbuf, mpbuf, msbuf, fT0, fR,
                  smem + 49152, tid);
    }
  } else {
    // ===================== W: z + comp + write-LSTM (2 rows) ==================
    int g = bid - 192, r0g = 2 * g;
    float* psum  = (float*)(smem);           // 32KB [2][4][1024]
    u32*  xh    = (u32*)(smem + 32768);      // 1KB
    float* comp  = (float*)(smem + 33792);   // [2][256]
    float* hw_f  = (float*)(smem + 35840);   // [2][256]
    float* m_f   = (float*)(smem + 37888);   // [2][256]
    float* wcs_l = (float*)(smem + 39936);   // [256]
    float* bc_l  = (float*)(smem + 40960);   // [256]
    float* redA  = (float*)(smem + 41984);   // [16]
    float* redB  = (float*)(smem + 42048);
    float* redC  = (float*)(smem + 42112);
    float* redD  = (float*)(smem + 42176);
    float* bE_l  = (float*)(smem + 43008);   // [1024]
    int row = tid >> 9, i = tid & 511;
    int brow = r0g + row;
    if (tid < 256){ wcs_l[tid] = wcs[tid]; bc_l[tid] = bcf[tid]; }
    bE_l[tid] = bE[tid];
    float cst = 0.f;
    if (i < 256){
      hw_f[row * 256 + i] = hw0[brow * 256 + i];
      cst = cw0[brow * 256 + i];
    }
    unsigned char mkA = mbuf[brow * 1024 + i];
    unsigned char mkB = mbuf[brow * 1024 + 512 + i];
    float zA = 0.f, zB = 0.f;
    __syncthreads();
    // scan duty first (publishes partials other W blocks need)
    scan_half(bid, M0, mbuf, hrf, spbuf, mpbuf, msbuf, fT0, fR,
              smem + 49152, tid);
    // prefetch step-0 hr/u (slot 0)
    pollk(fR + r0g, 2, 1u, tid);
    float hrv = 0.f, ureg = 0.f;
    if (i < 256){
      hrv  = alf(hrf + brow * 256 + i);
      ureg = alf(ubuf + brow * 256 + i);
    }

    for (int t = 0; t < kT; t++){
      float e = -INFINITY;
      if (t == 0){
        pollk(fT0 + 4 * g, 4, 1u, tid);
        int kA2 = 2 * brow, kB2 = 2 * brow + 1;
        float maxA = alf(msbuf + 2 * kA2), SAv = alf(msbuf + 2 * kA2 + 1);
        float maxB = alf(msbuf + 2 * kB2), SBv = alf(msbuf + 2 * kB2 + 1);
        float Gm = fmaxf(maxA, maxB);
        float eAc = expf(maxA - Gm), eBc = expf(maxB - Gm);
        float Sg = SAv * eAc + SBv * eBc;
        zA = expf(alf(spbuf + brow * 1024 + i) - Gm) / Sg;
        zB = expf(alf(spbuf + brow * 1024 + 512 + i) - Gm) / Sg;
        if (i < 256){
          float mv = (alf(mpbuf + kA2 * 256 + i) * eAc
                    + alf(mpbuf + kB2 * 256 + i) * eBc) / Sg;
          m_f[row * 256 + i] = mv;
        }
        __syncthreads();
        if (i < 128)
          xh[row * 128 + i] = packf16(m_f[row * 256 + 2 * i],
                                      m_f[row * 256 + 2 * i + 1]);
        __syncthreads();
        {  // vcm = Wc_m @ m0, both rows (one-time, local)
          int c = tid & 255, ks = tid >> 8;
          const u32* wp = Wcp + 32768 + (size_t)(ks * 32) * 256 + c;
          const u32* x0 = xh + ks * 32;
          const u32* x1 = xh + 128 + ks * 32;
          float a0 = 0.f, a1 = 0.f;
          #pragma unroll 8
          for (int ii = 0; ii < 32; ii++){
            u32 wv = wp[(size_t)ii * 256];
            a0 = dot2u(wv, x0[ii], a0);
            a1 = dot2u(wv, x1[ii], a1);
          }
          psum[ks * 512 + c] = a0;
          psum[ks * 512 + 256 + c] = a1;
        }
        __syncthreads();
        if (i < 256){
          float vcm = psum[row * 256 + i] + psum[512 + row * 256 + i]
                    + psum[1024 + row * 256 + i] + psum[1536 + row * 256 + i];
          e = ureg + vcm + bc_l[i];
        }
      } else {
        // 2-round z-update: s is a convex combination of S1,S2 (z in [0,1]),
        // so gm = max(S1,S2) is a valid exp-shift bound; Ab = 1-Cb (sum zn = 1).
        float v1 = (i < 256) ? hrv : 0.f;
        float v2 = (i < 256) ? hrv * hw_f[row * 256 + i] : 0.f;
        #pragma unroll
        for (int mm = 32; mm >= 1; mm >>= 1){
          v1 += __shfl_xor(v1, mm, 64);  v2 += __shfl_xor(v2, mm, 64);
        }
        if (lane == 0){ redA[w] = v1; redB[w] = v2; }
        __syncthreads();
        float S1 = 0.f, S2 = 0.f;
        #pragma unroll
        for (int k2 = 0; k2 < 8; k2++){
          S1 += redA[row * 8 + k2];  S2 += redB[row * 8 + k2];
        }
        float gm = fmaxf(S1, S2);
        float sA = mkA ? -INFINITY : (1.f - zA) * S1 + zA * S2;
        float sB = mkB ? -INFINITY : (1.f - zB) * S1 + zB * S2;
        float pA_ = expf(sA - gm), pB_ = expf(sB - gm);
        float ps = pA_ + pB_, pz = pA_ * zA + pB_ * zB;
        #pragma unroll
        for (int mm = 32; mm >= 1; mm >>= 1){
          ps += __shfl_xor(ps, mm, 64);  pz += __shfl_xor(pz, mm, 64);
        }
        if (lane == 0){ redC[w] = ps; redD[w] = pz; }
        __syncthreads();
        float Ss = 0.f, Pz = 0.f;
        #pragma unroll
        for (int k2 = 0; k2 < 8; k2++){
          Ss += redC[row * 8 + k2];  Pz += redD[row * 8 + k2];
        }
        float Cb = Pz / Ss, Ab = 1.f - Cb;
        zA = pA_ / Ss;  zB = pB_ / Ss;
        pollk(fGv + g, 1, (u32)(t + 1), tid);
        if (i < 256){
          float vc = alf(vcbuf + (t & 1) * 32768 + brow * 256 + i);
          e = ureg + Ab * wcs_l[i] + Cb * vc + bc_l[i];
        }
      }
      // comp: fixed-shift softmax pe = exp(e-4) (exact after normalization,
      // validated r3). Partials via redA (last read precedes 2 barriers).
      float pe = (i < 256) ? expf(e - 4.f) : 0.f;
      float ps2 = pe;
      #pragma unroll
      for (int mm = 32; mm >= 1; mm >>= 1) ps2 += __shfl_xor(ps2, mm, 64);
      if (lane == 0) redA[w] = ps2;
      if (i < 256) comp[row * 256 + i] = pe;
      __syncthreads();
      float esum = 0.f;
      #pragma unroll
      for (int k2 = 0; k2 < 8; k2++) esum += redA[row * 8 + k2];
      if (i < 128)
        xh[row * 128 + i] = packf16(comp[row * 256 + 2 * i],
                                    comp[row * 256 + 2 * i + 1]);
      __syncthreads();
      {  // Wih_w @ pe, both rows
        int cg = tid & 255, ks = tid >> 8;
        const uint4* wp = (const uint4*)WEp + (size_t)(ks * 32) * 256 + cg;
        const u32* x0 = xh + ks * 32;
        const u32* x1 = xh + 128 + ks * 32;
        float a0=0.f,a1=0.f,a2=0.f,a3=0.f,b0=0.f,b1=0.f,b2=0.f,b3=0.f;
        #pragma unroll 4
        for (int ii = 0; ii < 32; ii++){
          uint4 wv = wp[(size_t)ii * 256];
          u32 xp0 = x0[ii], xp1 = x1[ii];
          a0 = dot2u(wv.x, xp0, a0);  a1 = dot2u(wv.y, xp0, a1);
          a2 = dot2u(wv.z, xp0, a2);  a3 = dot2u(wv.w, xp0, a3);
          b0 = dot2u(wv.x, xp1, b0);  b1 = dot2u(wv.y, xp1, b1);
          b2 = dot2u(wv.z, xp1, b2);  b3 = dot2u(wv.w, xp1, b3);
        }
        float4 ra; ra.x=a0; ra.y=a1; ra.z=a2; ra.w=a3;
        float4 rb; rb.x=b0; rb.y=b1; rb.z=b2; rb.w=b3;
        *(float4*)&psum[ks * 1024 + cg * 4] = ra;
        *(float4*)&psum[4096 + ks * 1024 + cg * 4] = rb;
      }
      __syncthreads();
      pollk(fG + g, 1, (u32)(t + 1), tid);
      if (i < 256){
        float rinv = 1.f / esum;
        const float* gwp = gwbuf + (t & 1) * 131072 + brow * 1024;
        float si = psum[row*4096 + i]        + psum[row*4096 + 1024 + i]
                 + psum[row*4096 + 2048 + i] + psum[row*4096 + 3072 + i];
        float sf = psum[row*4096 + 256 + i]  + psum[row*4096 + 1280 + i]
                 + psum[row*4096 + 2304 + i] + psum[row*4096 + 3328 + i];
        float sg2= psum[row*4096 + 512 + i]  + psum[row*4096 + 1536 + i]
                 + psum[row*4096 + 2560 + i] + psum[row*4096 + 3584 + i];
        float so = psum[row*4096 + 768 + i]  + psum[row*4096 + 1792 + i]
                 + psum[row*4096 + 2816 + i] + psum[row*4096 + 3840 + i];
        float gi = bE_l[i]       + alf(gwp + i)       + si  * rinv;
        float gf = bE_l[256 + i] + alf(gwp + 256 + i) + sf  * rinv;
        float gg = bE_l[512 + i] + alf(gwp + 512 + i) + sg2 * rinv;
        float go = bE_l[768 + i] + alf(gwp + 768 + i) + so  * rinv;
        float i_ = 1.f / (1.f + expf(-gi));
        float f_ = 1.f / (1.f + expf(-gf));
        float g_ = tanhf(gg);
        float o_ = 1.f / (1.f + expf(-go));
        float c2 = f_ * cst + i_ * g_;
        cst = c2;
        float h = o_ * tanhf(c2);
        hw_f[row * 256 + i] = h;
        out[(size_t)t * 32768 + brow * 256 + i] = h;
        if (t == kT - 1){
          out[OUT_STATES + 65536 + brow * 256 + i] = h;
          out[OUT_STATES + 98304 + brow * 256 + i] = c2;
        }
      }
      __syncthreads();
      if (i < 128)
        asu(hwp + (t & 1) * 16384 + brow * 128 + i,
            packf16(hw_f[row * 256 + 2 * i], hw_f[row * 256 + 2 * i + 1]));
      __syncthreads();   // drain before flag
      if (tid == 0) asu(fW + g, (u32)(t + 1));
      if (t < kT - 1){
        // tail: prefetch hr/u(t+1); fR>=t+2 instantly satisfied (R runs 2 ahead)
        pollk(fR + r0g, 2, (u32)(t + 2), tid);
        if (i < 256){
          hrv  = alf(hrf + ((t + 1) & 1) * 32768 + brow * 256 + i);
          ureg = alf(ubuf + ((t + 1) & 1) * 32768 + brow * 256 + i);
        }
      }
    }
    // publish final z & hw for the M epilogue
    if (i < 256) asf(hwfin + brow * 256 + i, hw_f[row * 256 + i]);
    asf(zsbuf + brow * 1024 + i, zA);
    asf(zsbuf + brow * 1024 + 512 + i, zB);
    __syncthreads();   // drain before flag
    if (tid == 0) asu(fW + g, (u32)(kT + 1));
  }

  // ========== epilogue: every block writes half a row of M ==========
  {
    int mrow = bid >> 1, half = bid & 1;
    pollk(fW + (mrow >> 1), 1, (u32)(kT + 1), tid);
    float* zl  = (float*)(smem + 49152);   // [512]
    float* hwl = (float*)(smem + 51200);   // [256]
    if (tid < 512) zl[tid] = alf(zsbuf + mrow * 1024 + half * 512 + tid);
    else if (tid < 768) hwl[tid - 512] = alf(hwfin + mrow * 256 + (tid - 512));
    __syncthreads();
    float* Mout = out + OUT_M + (size_t)mrow * 262144 + (size_t)half * 131072;
    for (int it = 0; it < 32; it++){
      int idx = it * 1024 + tid;
      int l = idx >> 6, d4 = (idx & 63) << 2;
      float z = zl[l], omz = 1.f - z;
      float4 h4 = *(const float4*)&hwl[d4];
      float4 v;
      v.x = omz + h4.x * z;  v.y = omz + h4.y * z;
      v.z = omz + h4.z * z;  v.w = omz + h4.w * z;
      *(float4*)(Mout + (size_t)l * 256 + d4) = v;
    }
  }
}

extern "C" void kernel_launch(void* const* d_in, const int* in_sizes, int n_in,
                              void* d_out, int out_size, void* d_ws, size_t ws_size,
                              hipStream_t stream){
  const float* emb   = (const float*)d_in[0];
  const float* hr0   = (const float*)d_in[1];
  const float* cr0   = (const float*)d_in[2];
  const float* hw0   = (const float*)d_in[3];
  const float* cw0   = (const float*)d_in[4];
  const float* M0    = (const float*)d_in[5];
  const unsigned char* maskraw = (const unsigned char*)d_in[6];
  const float* Wih_r = (const float*)d_in[7];
  const float* Whh_r = (const float*)d_in[8];
  const float* bih_r = (const float*)d_in[9];
  const float* bhh_r = (const float*)d_in[10];
  const float* Wc    = (const float*)d_in[11];
  const float* bc    = (const float*)d_in[12];
  const float* Wih_w = (const float*)d_in[13];
  const float* Whh_w = (const float*)d_in[14];
  const float* bih_w = (const float*)d_in[15];
  const float* bhh_w = (const float*)d_in[16];
  float* out = (float*)d_out;

  char* ws = (char*)d_ws;
  u32*  WAp   = (u32*)(ws);                       // 1 MB
  u32*  WEp   = (u32*)(ws + 1048576);             // 1 MB
  u32*  Wcp   = (u32*)(ws + 2097152);             // 256 KB
  float* bA   = (float*)(ws + 2359296);           // 4 KB
  float* bE   = (float*)(ws + 2363392);           // 4 KB
  float* bcf  = (float*)(ws + 2367488);           // 1 KB
  float* wcs  = (float*)(ws + 2368512);           // 1 KB
  unsigned char* mbuf = (unsigned char*)(ws + 2369536);  // 128 KB
  u32*  flags = (u32*)(ws + 2500608);             // 4 KB (768 zeroed)
  float* hrf  = (float*)(ws + 2504704);           // 256 KB (2 slots)
  float* ubuf = (float*)(ws + 2766848);           // 256 KB
  float* gwbuf= (float*)(ws + 3291136);           // 1 MB (2 slots)
  u32*  hwp   = (u32*)(ws + 4339712);             // 128 KB
  float* zsbuf= (float*)(ws + 4470784);           // 512 KB
  float* hwfin= (float*)(ws + 4995072);           // 128 KB
  float* spbuf= (float*)(ws + 5126144);           // 512 KB (raw t0 scores)
  float* mpbuf= (float*)(ws + 5650432);           // 256 KB (t0 partial m)
  float* msbuf= (float*)(ws + 5912576);           // 2 KB   (t0 {max,S})
  u32*  gxp   = (u32*)(ws + 5914624);             // 8 MB
  float* vcbuf= (float*)(ws + 14303232);          // 256 KB (2 slots)

  k_prep<<<dim3(708), dim3(1024), 0, stream>>>(
      Wih_r, Whh_r, bih_r, bhh_r, Wc, bc, Wih_w, Whh_w, bih_w, bhh_w,
      maskraw, WAp, WEp, Wcp, bA, bE, bcf, wcs, mbuf, flags);
  k_pre<<<dim3(32, 8), dim3(1024), 0, stream>>>(emb, WAp, gxp);
  k_main<<<dim3(256), dim3(1024), 0, stream>>>(
      hr0, cr0, hw0, cw0, M0, WAp, WEp, Wcp, bA, bE, bcf, wcs, mbuf, gxp,
      hrf, ubuf, vcbuf, gwbuf, hwp, zsbuf, hwfin, spbuf, mpbuf, msbuf,
      flags, out);
}